// Round 7
// baseline (430.228 us; speedup 1.0000x reference)
//
#include <hip/hip_runtime.h>

typedef __attribute__((ext_vector_type(4))) float f32x4;
typedef __attribute__((ext_vector_type(8))) short s16x8;

#define MFMA16(a,b,c) __builtin_amdgcn_mfma_f32_16x16x32_bf16(a,b,c,0,0,0)

__device__ __forceinline__ unsigned short f2bf(float f){
  unsigned u = __float_as_uint(f);
  u += 0x7FFFu + ((u >> 16) & 1u);
  return (unsigned short)(u >> 16);
}

// ---------------- fused x->bf16 cast + weight prep -------------------------
// blocks [0, 12544): xcast ; blocks [12544, 13056): weight/bias/bias-tile prep
__global__ void k_prep2(const float* __restrict__ x,
                        const float* __restrict__ qkv_w,   // (512,1536)
                        const float* __restrict__ qkv_b,   // (1536)
                        const float* __restrict__ proj_w,  // (512,512)
                        const float* __restrict__ btab,    // (169,16)
                        unsigned short* __restrict__ xb,      // (50176,512) bf16
                        unsigned short* __restrict__ wqkv_t,  // (1536,512) bf16
                        unsigned short* __restrict__ wproj_t, // (512,512) bf16
                        float* __restrict__ bqkv_s,           // (1536) f32
                        float* __restrict__ bias_t)           // (16,64,64) f32
{
  if (blockIdx.x < 12544){
    const int i = blockIdx.x * 256 + threadIdx.x;   // one 8-elem chunk
    const float* p = x + (size_t)i*8;
    f32x4 v0 = *(const f32x4*)p, v1 = *(const f32x4*)(p+4);
    s16x8 t;
    t[0]=(short)f2bf(v0[0]); t[1]=(short)f2bf(v0[1]);
    t[2]=(short)f2bf(v0[2]); t[3]=(short)f2bf(v0[3]);
    t[4]=(short)f2bf(v1[0]); t[5]=(short)f2bf(v1[1]);
    t[6]=(short)f2bf(v1[2]); t[7]=(short)f2bf(v1[3]);
    *(s16x8*)(xb + (size_t)i*8) = t;
    return;
  }
  const float scale = 0.17677669529663687f; // 32^-0.5
  int tid = (blockIdx.x - 12544) * 256 + threadIdx.x;
  int np  = 512 * 256;
  for (int i = tid; i < 1536*512; i += np){
    int c = i >> 9, k = i & 511;
    float w = qkv_w[k*1536 + c];
    if (c < 512) w *= scale;
    wqkv_t[i] = f2bf(w);
  }
  for (int i = tid; i < 512*512; i += np){
    int c = i >> 9, k = i & 511;
    wproj_t[i] = f2bf(proj_w[k*512 + c]);
  }
  for (int i = tid; i < 1536; i += np){
    float bv = qkv_b[i];
    if (i < 512) bv *= scale;
    bqkv_s[i] = bv;
  }
  // per-head bias tile [h][row][col]; column mask folded in (-1e30 @ col>=49)
  for (int i = tid; i < 16*64*64; i += np){
    int hh = i >> 12, rc = i & 4095, row = rc >> 6, col = rc & 63;
    float v;
    if (col >= 49)      v = -1e30f;
    else if (row >= 49) v = 0.f;
    else {
      int qy = row/7, qx = row%7, ky = col/7, kx = col%7;
      v = btab[((qy-ky+6)*13 + (qx-kx+6))*16 + hh];
    }
    bias_t[i] = v;
  }
}

// ---------------- fused qkv GEMM + window attention ------------------------
// grid: 1024 windows * 4 head-groups; block 256 = 4 waves; wave <-> one head.
// NO barriers, NO vT in LDS (V redistributed via in-wave shuffles).
// Per-wave LDS shorts: q[64][40]=2560 | k[64][40]=2560  (P[64][72]=4608 and
// O[64][40] overlay q+k). 5120 shorts = 10240 B/wave -> 40960 B/block.
__global__ __launch_bounds__(256, 3) void k_qkv_attn6(
    const unsigned short* __restrict__ xb,    // (50176,512) bf16
    const unsigned short* __restrict__ wqkv_t,// (1536,512) bf16 (q pre-scaled)
    const float* __restrict__ bqkv_s,         // (1536) f32 (q pre-scaled)
    const float* __restrict__ bias_t,         // (16,64,64) f32, mask folded
    unsigned short* __restrict__ att)         // (1024,49,512) bf16
{
  __shared__ unsigned short lds[4*5120];
  const int lane = threadIdx.x & 63;
  const int wave = threadIdx.x >> 6;
  const int b    = blockIdx.x >> 2;
  const int h    = ((blockIdx.x & 3) << 2) | wave;
  const int l16  = lane & 15;
  const int lg   = lane >> 4;   // 0..3
  const f32x4 ZERO4 = {0.f, 0.f, 0.f, 0.f};

  unsigned short* q_lds = lds + wave*5120;   // [64][40]
  unsigned short* k_lds = q_lds + 2560;      // [64][40]
  unsigned short* p_lds = q_lds;             // [64][72] overlay (q+k dead)

  const unsigned short* xwin = xb + (size_t)b*49*512;
  const int cbase = h * 32;

  // per-lane A-row pointers
  const unsigned short* xrow[4];
  bool xok[4];
  #pragma unroll
  for (int rt=0;rt<4;++rt){
    const int n = rt*16 + l16;
    xok[rt]  = (n < 49);
    xrow[rt] = xwin + (size_t)n*512 + lg*8;
  }
  // per-lane B pointers
  const unsigned short* bptr[6];
  #pragma unroll
  for (int wq=0; wq<3; ++wq)
    #pragma unroll
    for (int ct=0; ct<2; ++ct)
      bptr[wq*2+ct] = wqkv_t + (size_t)(wq*512 + cbase + ct*16 + l16)*512 + lg*8;

  // ---- qkv GEMM: 64 tokens x (3 x 32) cols for head h ----
  f32x4 acc[3][4][2];
  #pragma unroll
  for (int a=0;a<3;++a)
    #pragma unroll
    for (int rt=0;rt<4;++rt)
      #pragma unroll
      for (int ct=0;ct<2;++ct)
        acc[a][rt][ct] = ZERO4;

  #pragma unroll 2
  for (int ks = 0; ks < 16; ++ks){
    s16x8 afrag[4];
    #pragma unroll
    for (int rt=0; rt<4; ++rt){
      s16x8 t_ = {0,0,0,0,0,0,0,0};
      if (xok[rt]) t_ = *(const s16x8*)(xrow[rt] + ks*32);
      afrag[rt] = t_;
    }
    s16x8 bfrag[6];
    #pragma unroll
    for (int i=0;i<6;++i)
      bfrag[i] = *(const s16x8*)(bptr[i] + ks*32);

    #pragma unroll
    for (int wq=0;wq<3;++wq)
      #pragma unroll
      for (int rt=0;rt<4;++rt)
        #pragma unroll
        for (int ct=0;ct<2;++ct)
          acc[wq][rt][ct] = MFMA16(afrag[rt], bfrag[wq*2+ct], acc[wq][rt][ct]);
  }

  // ---- epilogue: q,k -> LDS (row-major); v -> packed bf16 registers ----
  uint2 vpk[4][2];   // [rt][ct]: V rows rt*16+lg*4..+3, col ct*16+l16 (bf16x4)
  #pragma unroll
  for (int wq=0; wq<3; ++wq){
    #pragma unroll
    for (int ct=0; ct<2; ++ct){
      const int c = wq*512 + cbase + ct*16 + l16;
      const float bv = bqkv_s[c];
      #pragma unroll
      for (int rt=0; rt<4; ++rt){
        f32x4 vv = acc[wq][rt][ct];
        const int row0 = rt*16 + lg*4;
        if (wq == 0){
          #pragma unroll
          for (int r=0;r<4;++r) q_lds[(row0+r)*40 + ct*16 + l16] = f2bf(vv[r]+bv);
        } else if (wq == 1){
          #pragma unroll
          for (int r=0;r<4;++r) k_lds[(row0+r)*40 + ct*16 + l16] = f2bf(vv[r]+bv);
        } else {
          uint2 pk;
          pk.x = (unsigned)f2bf(vv[0]+bv) | ((unsigned)f2bf(vv[1]+bv) << 16);
          pk.y = (unsigned)f2bf(vv[2]+bv) | ((unsigned)f2bf(vv[3]+bv) << 16);
          vpk[rt][ct] = pk;
        }
      }
    }
  }

  // ---- scores S = q @ k^T ----
  s16x8 aq[4], bk[4];
  #pragma unroll
  for (int t=0;t<4;++t){
    aq[t] = *(const s16x8*)&q_lds[(t*16+l16)*40 + lg*8];
    bk[t] = *(const s16x8*)&k_lds[(t*16+l16)*40 + lg*8];
  }
  f32x4 sacc[4][4];
  #pragma unroll
  for (int rt=0;rt<4;++rt)
    #pragma unroll
    for (int ct=0;ct<4;++ct)
      sacc[rt][ct] = MFMA16(aq[rt], bk[ct], ZERO4);

  // ---- softmax: bias (mask folded), batched 16-row reductions ----
  const float* biash = bias_t + (h << 12);
  float pm[4][4];
  #pragma unroll
  for (int rt=0;rt<4;++rt){
    #pragma unroll
    for (int r=0;r<4;++r){
      const int row = rt*16 + lg*4 + r;
      const float* brow = biash + (row << 6) + l16;
      float s0 = sacc[rt][0][r] + brow[0];
      float s1 = sacc[rt][1][r] + brow[16];
      float s2 = sacc[rt][2][r] + brow[32];
      float s3 = sacc[rt][3][r] + brow[48];
      sacc[rt][0][r]=s0; sacc[rt][1][r]=s1; sacc[rt][2][r]=s2; sacc[rt][3][r]=s3;
      pm[rt][r] = fmaxf(fmaxf(s0,s1), fmaxf(s2,s3));
    }
  }
  #pragma unroll
  for (int d=1; d<16; d<<=1)
    #pragma unroll
    for (int rt=0;rt<4;++rt)
      #pragma unroll
      for (int r=0;r<4;++r)
        pm[rt][r] = fmaxf(pm[rt][r], __shfl_xor(pm[rt][r], d));

  float ps[4][4];
  #pragma unroll
  for (int rt=0;rt<4;++rt){
    #pragma unroll
    for (int r=0;r<4;++r){
      const float m = pm[rt][r];
      float e0 = __expf(sacc[rt][0][r]-m), e1 = __expf(sacc[rt][1][r]-m);
      float e2 = __expf(sacc[rt][2][r]-m), e3 = __expf(sacc[rt][3][r]-m);
      sacc[rt][0][r]=e0; sacc[rt][1][r]=e1; sacc[rt][2][r]=e2; sacc[rt][3][r]=e3;
      ps[rt][r] = e0+e1+e2+e3;
    }
  }
  #pragma unroll
  for (int d=1; d<16; d<<=1)
    #pragma unroll
    for (int rt=0;rt<4;++rt)
      #pragma unroll
      for (int r=0;r<4;++r)
        ps[rt][r] += __shfl_xor(ps[rt][r], d);

  #pragma unroll
  for (int rt=0;rt<4;++rt){
    #pragma unroll
    for (int r=0;r<4;++r){
      const int row = rt*16 + lg*4 + r;
      const float inv = 1.f / ps[rt][r];
      p_lds[row*72 +      l16] = f2bf(sacc[rt][0][r]*inv);
      p_lds[row*72 + 16 + l16] = f2bf(sacc[rt][1][r]*inv);
      p_lds[row*72 + 32 + l16] = f2bf(sacc[rt][2][r]*inv);
      p_lds[row*72 + 48 + l16] = f2bf(sacc[rt][3][r]*inv);
    }
  }

  // ---- O = P @ v ;  V B-fragments via in-wave shuffles -------------------
  // Target lane (l16,lg) needs V[kt*32+lg*8+j][ct*16+l16], j=0..7.
  // Source lanes: srcA = l16 + 32*(lg&1) (j=0..3), srcB = srcA+16 (j=4..7);
  // source rt' = 2*kt + (lg>>1).
  const int srcA = l16 + ((lg & 1) << 5);
  const int srcB = srcA + 16;
  const bool hiSel = (lg >> 1) != 0;

  f32x4 oacc[4][2];
  #pragma unroll
  for (int rt=0;rt<4;++rt)
    #pragma unroll
    for (int ct=0;ct<2;++ct)
      oacc[rt][ct] = ZERO4;

  #pragma unroll
  for (int kt=0; kt<2; ++kt){
    s16x8 ap[4], bv2[2];
    #pragma unroll
    for (int rt=0;rt<4;++rt)
      ap[rt] = *(const s16x8*)&p_lds[(rt*16+l16)*72 + kt*32 + lg*8];
    #pragma unroll
    for (int ct=0;ct<2;++ct){
      // both rt' candidates, then select by lg>>1
      unsigned a0x = (unsigned)__shfl((int)vpk[2*kt  ][ct].x, srcA, 64);
      unsigned a0y = (unsigned)__shfl((int)vpk[2*kt  ][ct].y, srcA, 64);
      unsigned a1x = (unsigned)__shfl((int)vpk[2*kt+1][ct].x, srcA, 64);
      unsigned a1y = (unsigned)__shfl((int)vpk[2*kt+1][ct].y, srcA, 64);
      unsigned b0x = (unsigned)__shfl((int)vpk[2*kt  ][ct].x, srcB, 64);
      unsigned b0y = (unsigned)__shfl((int)vpk[2*kt  ][ct].y, srcB, 64);
      unsigned b1x = (unsigned)__shfl((int)vpk[2*kt+1][ct].x, srcB, 64);
      unsigned b1y = (unsigned)__shfl((int)vpk[2*kt+1][ct].y, srcB, 64);
      union { s16x8 v; unsigned u[4]; } fr;
      fr.u[0] = hiSel ? a1x : a0x;
      fr.u[1] = hiSel ? a1y : a0y;
      fr.u[2] = hiSel ? b1x : b0x;
      fr.u[3] = hiSel ? b1y : b0y;
      bv2[ct] = fr.v;
    }
    #pragma unroll
    for (int rt=0;rt<4;++rt)
      #pragma unroll
      for (int ct=0;ct<2;++ct)
        oacc[rt][ct] = MFMA16(ap[rt], bv2[ct], oacc[rt][ct]);
  }

  // ---- restage O through LDS for coalesced bf16 stores ----
  unsigned short* o_lds = p_lds;  // [64][40]
  #pragma unroll
  for (int rt=0;rt<4;++rt)
    #pragma unroll
    for (int ct=0;ct<2;++ct){
      const int row0 = rt*16 + lg*4;
      f32x4 vv = oacc[rt][ct];
      #pragma unroll
      for (int r=0;r<4;++r)
        o_lds[(row0+r)*40 + ct*16 + l16] = f2bf(vv[r]);
    }
  unsigned short* attb = att + (size_t)b*49*512 + h*32;
  for (int i = lane; i < 49*4; i += 64){
    const int row = i >> 2, seg = i & 3;
    *(s16x8*)&attb[(size_t)row*512 + seg*8] = *(const s16x8*)&o_lds[row*40 + seg*8];
  }
}

// ---------------- fallback (f32 x direct, small ws) ------------------------
__global__ __launch_bounds__(256, 2) void k_qkv_attn_f32(
    const float* __restrict__ x,
    const unsigned short* __restrict__ wqkv_t,
    const float* __restrict__ bqkv_s,
    const float* __restrict__ btab,
    unsigned short* __restrict__ att)
{
  __shared__ unsigned short lds[4*7424];
  const int lane = threadIdx.x & 63;
  const int wave = threadIdx.x >> 6;
  const int b    = blockIdx.x >> 2;
  const int h    = ((blockIdx.x & 3) << 2) | wave;
  const int l16  = lane & 15;
  const int lg   = lane >> 4;
  const f32x4 ZERO4 = {0.f, 0.f, 0.f, 0.f};

  unsigned short* q_lds = lds + wave*7424;
  unsigned short* k_lds = q_lds + 2560;
  unsigned short* vT    = q_lds + 5120;
  unsigned short* p_lds = q_lds;

  f32x4 acc[3][4][2];
  #pragma unroll
  for (int a=0;a<3;++a)
    #pragma unroll
    for (int rt=0;rt<4;++rt)
      #pragma unroll
      for (int ct=0;ct<2;++ct)
        acc[a][rt][ct] = ZERO4;

  const float* xbp = x + (size_t)b * 49 * 512;
  const int cbase = h * 32;

  #pragma unroll 2
  for (int ks = 0; ks < 16; ++ks){
    const int k0 = ks*32 + lg*8;
    s16x8 afrag[4];
    #pragma unroll
    for (int rt=0; rt<4; ++rt){
      const int n = rt*16 + l16;
      f32x4 v0 = ZERO4, v1 = ZERO4;
      if (n < 49){
        const float* p = xbp + n*512 + k0;
        v0 = *(const f32x4*)p;
        v1 = *(const f32x4*)(p + 4);
      }
      s16x8 t;
      t[0]=(short)f2bf(v0[0]); t[1]=(short)f2bf(v0[1]);
      t[2]=(short)f2bf(v0[2]); t[3]=(short)f2bf(v0[3]);
      t[4]=(short)f2bf(v1[0]); t[5]=(short)f2bf(v1[1]);
      t[6]=(short)f2bf(v1[2]); t[7]=(short)f2bf(v1[3]);
      afrag[rt] = t;
    }
    s16x8 bfrag[3][2];
    #pragma unroll
    for (int wq=0;wq<3;++wq)
      #pragma unroll
      for (int ct=0;ct<2;++ct){
        const int c = wq*512 + cbase + ct*16 + l16;
        bfrag[wq][ct] = *(const s16x8*)(wqkv_t + (size_t)c*512 + k0);
      }
    #pragma unroll
    for (int wq=0;wq<3;++wq)
      #pragma unroll
      for (int rt=0;rt<4;++rt)
        #pragma unroll
        for (int ct=0;ct<2;++ct)
          acc[wq][rt][ct] = MFMA16(afrag[rt], bfrag[wq][ct], acc[wq][rt][ct]);
  }

  #pragma unroll
  for (int wq=0; wq<3; ++wq){
    #pragma unroll
    for (int ct=0; ct<2; ++ct){
      const int c = wq*512 + cbase + ct*16 + l16;
      const float bv = bqkv_s[c];
      #pragma unroll
      for (int rt=0; rt<4; ++rt){
        f32x4 vv = acc[wq][rt][ct];
        const int row0 = rt*16 + lg*4;
        if (wq == 0){
          #pragma unroll
          for (int r=0;r<4;++r) q_lds[(row0+r)*40 + ct*16 + l16] = f2bf(vv[r]+bv);
        } else if (wq == 1){
          #pragma unroll
          for (int r=0;r<4;++r) k_lds[(row0+r)*40 + ct*16 + l16] = f2bf(vv[r]+bv);
        } else {
          ushort4 pk;
          pk.x=f2bf(vv[0]+bv); pk.y=f2bf(vv[1]+bv);
          pk.z=f2bf(vv[2]+bv); pk.w=f2bf(vv[3]+bv);
          *(ushort4*)&vT[(ct*16+l16)*72 + row0] = pk;
        }
      }
    }
  }

  s16x8 aq[4], bk[4];
  #pragma unroll
  for (int t=0;t<4;++t){
    aq[t] = *(const s16x8*)&q_lds[(t*16+l16)*40 + lg*8];
    bk[t] = *(const s16x8*)&k_lds[(t*16+l16)*40 + lg*8];
  }
  f32x4 sacc[4][4];
  #pragma unroll
  for (int rt=0;rt<4;++rt)
    #pragma unroll
    for (int ct=0;ct<4;++ct)
      sacc[rt][ct] = MFMA16(aq[rt], bk[ct], ZERO4);

  int colv[4], kyv[4], kxv[4];
  #pragma unroll
  for (int ct=0;ct<4;++ct){
    colv[ct] = ct*16 + l16;
    kyv[ct]  = colv[ct] / 7;
    kxv[ct]  = colv[ct] % 7;
  }
  #pragma unroll
  for (int rt=0;rt<4;++rt){
    #pragma unroll
    for (int r=0;r<4;++r){
      const int row = rt*16 + lg*4 + r;
      const int qy = row / 7, qx = row % 7;
      float sv[4];
      #pragma unroll
      for (int ct=0;ct<4;++ct){
        float s = sacc[rt][ct][r];
        if (row < 49 && colv[ct] < 49){
          const int idx = (qy - kyv[ct] + 6)*13 + (qx - kxv[ct] + 6);
          s += btab[idx*16 + h];
        }
        if (colv[ct] >= 49) s = -1e30f;
        else if (row >= 49) s = 0.f;
        sv[ct] = s;
      }
      float m = fmaxf(fmaxf(sv[0],sv[1]), fmaxf(sv[2],sv[3]));
      #pragma unroll
      for (int d=1; d<16; d<<=1) m = fmaxf(m, __shfl_xor(m, d));
      float e0 = __expf(sv[0]-m), e1 = __expf(sv[1]-m);
      float e2 = __expf(sv[2]-m), e3 = __expf(sv[3]-m);
      float sum = e0+e1+e2+e3;
      #pragma unroll
      for (int d=1; d<16; d<<=1) sum += __shfl_xor(sum, d);
      const float inv = 1.f / sum;
      p_lds[row*72 + colv[0]] = f2bf(e0*inv);
      p_lds[row*72 + colv[1]] = f2bf(e1*inv);
      p_lds[row*72 + colv[2]] = f2bf(e2*inv);
      p_lds[row*72 + colv[3]] = f2bf(e3*inv);
    }
  }

  f32x4 oacc[4][2];
  #pragma unroll
  for (int rt=0;rt<4;++rt)
    #pragma unroll
    for (int ct=0;ct<2;++ct)
      oacc[rt][ct] = ZERO4;
  #pragma unroll
  for (int kt=0; kt<2; ++kt){
    s16x8 ap[4], bv2[2];
    #pragma unroll
    for (int rt=0;rt<4;++rt)
      ap[rt] = *(const s16x8*)&p_lds[(rt*16+l16)*72 + kt*32 + lg*8];
    #pragma unroll
    for (int ct=0;ct<2;++ct)
      bv2[ct] = *(const s16x8*)&vT[(ct*16+l16)*72 + kt*32 + lg*8];
    #pragma unroll
    for (int rt=0;rt<4;++rt)
      #pragma unroll
      for (int ct=0;ct<2;++ct)
        oacc[rt][ct] = MFMA16(ap[rt], bv2[ct], oacc[rt][ct]);
  }

  unsigned short* o_lds = p_lds;
  #pragma unroll
  for (int rt=0;rt<4;++rt)
    #pragma unroll
    for (int ct=0;ct<2;++ct){
      const int row0 = rt*16 + lg*4;
      f32x4 vv = oacc[rt][ct];
      #pragma unroll
      for (int r=0;r<4;++r)
        o_lds[(row0+r)*40 + ct*16 + l16] = f2bf(vv[r]);
    }
  unsigned short* attb = att + (size_t)b*49*512 + h*32;
  for (int i = lane; i < 49*4; i += 64){
    const int row = i >> 2, seg = i & 3;
    *(s16x8*)&attb[(size_t)row*512 + seg*8] = *(const s16x8*)&o_lds[row*40 + seg*8];
  }
}

// ---------------- proj GEMM: out = att(bf16) @ proj_w + b, fp32 out --------
__global__ __launch_bounds__(256) void k_proj(
    const unsigned short* __restrict__ att,    // (50176,512) bf16
    const unsigned short* __restrict__ wproj_t,// (512,512) bf16, [c][k]
    const float* __restrict__ proj_b,          // (512)
    float* __restrict__ out)                   // (50176,512) f32
{
  const int lane = threadIdx.x & 63;
  const int wave = threadIdx.x >> 6;
  const int l16  = lane & 15;
  const int lg   = lane >> 4;
  const int mb = blockIdx.x >> 2;
  const int nb = blockIdx.x & 3;
  const int m0 = mb*128 + (wave>>1)*64;
  const int n0 = nb*128 + (wave&1)*64;
  const f32x4 ZERO4 = {0.f, 0.f, 0.f, 0.f};

  f32x4 acc[4][4];
  #pragma unroll
  for (int rt=0;rt<4;++rt)
    #pragma unroll
    for (int ct=0;ct<4;++ct)
      acc[rt][ct] = ZERO4;

  #pragma unroll 2
  for (int ks=0; ks<16; ++ks){
    const int k0 = ks*32 + lg*8;
    s16x8 a[4], bw[4];
    #pragma unroll
    for (int t=0;t<4;++t){
      a[t]  = *(const s16x8*)(att     + (size_t)(m0 + t*16 + l16)*512 + k0);
      bw[t] = *(const s16x8*)(wproj_t + (size_t)(n0 + t*16 + l16)*512 + k0);
    }
    #pragma unroll
    for (int rt=0;rt<4;++rt)
      #pragma unroll
      for (int ct=0;ct<4;++ct)
        acc[rt][ct] = MFMA16(a[rt], bw[ct], acc[rt][ct]);
  }

  #pragma unroll
  for (int ct=0;ct<4;++ct){
    const float bv = proj_b[n0 + ct*16 + l16];
    #pragma unroll
    for (int rt=0;rt<4;++rt){
      const int row = m0 + rt*16 + lg*4;
      #pragma unroll
      for (int r=0;r<4;++r)
        out[(size_t)(row+r)*512 + n0 + ct*16 + l16] = acc[rt][ct][r] + bv;
    }
  }
}

// ---------------- launcher -------------------------------------------------
extern "C" void kernel_launch(void* const* d_in, const int* in_sizes, int n_in,
                              void* d_out, int out_size, void* d_ws, size_t ws_size,
                              hipStream_t stream)
{
  const float* x      = (const float*)d_in[0];
  const float* qkv_w  = (const float*)d_in[1];
  const float* qkv_b  = (const float*)d_in[2];
  const float* btab   = (const float*)d_in[3];
  const float* proj_w = (const float*)d_in[4];
  const float* proj_b = (const float*)d_in[5];
  float* out = (float*)d_out;

  char* ws = (char*)d_ws;
  const size_t ATT = 51380224ULL;   // 50176*512*2
  const size_t XB  = 51380224ULL;
  const size_t WQ  = 1572864ULL;
  const size_t WP  = 524288ULL;
  const size_t BT  = 262144ULL;     // 16*64*64*4
  const size_t need_big = ATT + XB + WQ + WP + BT + 8192;

  if (ws_size >= need_big){
    unsigned short* att     = (unsigned short*)ws;
    unsigned short* xbb     = (unsigned short*)(ws + ATT);
    unsigned short* wqkv_t  = (unsigned short*)(ws + ATT + XB);
    unsigned short* wproj_t = (unsigned short*)(ws + ATT + XB + WQ);
    float*          bias_t  = (float*)(ws + ATT + XB + WQ + WP);
    float*          bqkv_s  = (float*)(ws + ATT + XB + WQ + WP + BT);

    k_prep2<<<12544 + 512, 256, 0, stream>>>(x, qkv_w, qkv_b, proj_w, btab,
                                             xbb, wqkv_t, wproj_t, bqkv_s, bias_t);
    k_qkv_attn6<<<1024*4, 256, 0, stream>>>(xbb, wqkv_t, bqkv_s, bias_t, att);
    k_proj<<<392*4, 256, 0, stream>>>(att, wproj_t, proj_b, out);
  } else {
    unsigned short* att     = (unsigned short*)ws;
    unsigned short* wqkv_t  = (unsigned short*)(ws + ATT);
    unsigned short* wproj_t = (unsigned short*)(ws + ATT + WQ);
    float*          bqkv_s  = (float*)(ws + ATT + WQ + WP);

    k_prep2<<<12544 + 512, 256, 0, stream>>>(x, qkv_w, qkv_b, proj_w, btab,
                                             att /*scratch, overwritten later*/,
                                             wqkv_t, wproj_t, bqkv_s,
                                             (float*)(ws + ATT + WQ + WP + 8192));
    k_qkv_attn_f32<<<1024*4, 256, 0, stream>>>(x, wqkv_t, bqkv_s, btab, att);
    k_proj<<<392*4, 256, 0, stream>>>(att, wproj_t, proj_b, out);
  }
}

// Round 8
// 358.307 us; speedup vs baseline: 1.2007x; 1.2007x over previous
//
#include <hip/hip_runtime.h>

typedef __attribute__((ext_vector_type(4))) float f32x4;
typedef __attribute__((ext_vector_type(8))) short s16x8;

#define MFMA16(a,b,c) __builtin_amdgcn_mfma_f32_16x16x32_bf16(a,b,c,0,0,0)

__device__ __forceinline__ unsigned short f2bf(float f){
  unsigned u = __float_as_uint(f);
  u += 0x7FFFu + ((u >> 16) & 1u);
  return (unsigned short)(u >> 16);
}

__device__ __forceinline__ void gload_lds16(const unsigned short* g, unsigned short* l){
  __builtin_amdgcn_global_load_lds(
      (const __attribute__((address_space(1))) unsigned int*)(const void*)g,
      (__attribute__((address_space(3))) unsigned int*)(void*)l,
      16, 0, 0);
}

// ---------------- fused x->bf16 cast + weight prep -------------------------
// blocks [0, 12544): xcast ; blocks [12544, 13056): weight/bias/bias-tile prep
__global__ void k_prep2(const float* __restrict__ x,
                        const float* __restrict__ qkv_w,   // (512,1536)
                        const float* __restrict__ qkv_b,   // (1536)
                        const float* __restrict__ proj_w,  // (512,512)
                        const float* __restrict__ btab,    // (169,16)
                        unsigned short* __restrict__ xb,      // (50176,512) bf16
                        unsigned short* __restrict__ wqkv_t,  // (1536,512) bf16
                        unsigned short* __restrict__ wproj_t, // (512,512) bf16
                        float* __restrict__ bqkv_s,           // (1536) f32
                        float* __restrict__ bias_t)           // (16,64,64) f32
{
  if (blockIdx.x < 12544){
    const int i = blockIdx.x * 256 + threadIdx.x;   // one 8-elem chunk
    const float* p = x + (size_t)i*8;
    f32x4 v0 = *(const f32x4*)p, v1 = *(const f32x4*)(p+4);
    s16x8 t;
    t[0]=(short)f2bf(v0[0]); t[1]=(short)f2bf(v0[1]);
    t[2]=(short)f2bf(v0[2]); t[3]=(short)f2bf(v0[3]);
    t[4]=(short)f2bf(v1[0]); t[5]=(short)f2bf(v1[1]);
    t[6]=(short)f2bf(v1[2]); t[7]=(short)f2bf(v1[3]);
    *(s16x8*)(xb + (size_t)i*8) = t;
    return;
  }
  const float scale = 0.17677669529663687f; // 32^-0.5
  int tid = (blockIdx.x - 12544) * 256 + threadIdx.x;
  int np  = 512 * 256;
  for (int i = tid; i < 1536*512; i += np){
    int c = i >> 9, k = i & 511;
    float w = qkv_w[k*1536 + c];
    if (c < 512) w *= scale;
    wqkv_t[i] = f2bf(w);
  }
  for (int i = tid; i < 512*512; i += np){
    int c = i >> 9, k = i & 511;
    wproj_t[i] = f2bf(proj_w[k*512 + c]);
  }
  for (int i = tid; i < 1536; i += np){
    float bv = qkv_b[i];
    if (i < 512) bv *= scale;
    bqkv_s[i] = bv;
  }
  // per-head bias tile [h][row][col]; column mask folded in (-1e30 @ col>=49)
  for (int i = tid; i < 16*64*64; i += np){
    int hh = i >> 12, rc = i & 4095, row = rc >> 6, col = rc & 63;
    float v;
    if (col >= 49)      v = -1e30f;
    else if (row >= 49) v = 0.f;
    else {
      int qy = row/7, qx = row%7, ky = col/7, kx = col%7;
      v = btab[((qy-ky+6)*13 + (qx-kx+6))*16 + hh];
    }
    bias_t[i] = v;
  }
}

// ---------------- fused qkv GEMM + window attention ------------------------
// grid: 1024 windows * 4 head-groups; block 256 = 4 waves; wave <-> one head.
// Hybrid: shared x-tile staged via global_load_lds (R5) + shuffle-V (R7).
// LDS: per-wave q[64][40]+k[64][40] = 5120 shorts (P[64][72] overlays)
//      + shared x dbuf [2][64][32] = 4096 shorts. Block = 49152 B -> 3/CU.
__global__ __launch_bounds__(256, 3) void k_qkv_attn7(
    const unsigned short* __restrict__ xb,    // (50176,512) bf16
    const unsigned short* __restrict__ wqkv_t,// (1536,512) bf16 (q pre-scaled)
    const float* __restrict__ bqkv_s,         // (1536) f32 (q pre-scaled)
    const float* __restrict__ bias_t,         // (16,64,64) f32, mask folded
    unsigned short* __restrict__ att)         // (1024,49,512) bf16
{
  __shared__ unsigned short lds[4*5120 + 2*2048];
  const int lane = threadIdx.x & 63;
  const int wave = threadIdx.x >> 6;
  const int b    = blockIdx.x >> 2;
  const int h    = ((blockIdx.x & 3) << 2) | wave;
  const int l16  = lane & 15;
  const int lg   = lane >> 4;   // 0..3
  const f32x4 ZERO4 = {0.f, 0.f, 0.f, 0.f};

  unsigned short* q_lds  = lds + wave*5120;   // [64][40]
  unsigned short* k_lds  = q_lds + 2560;      // [64][40]
  unsigned short* p_lds  = q_lds;             // [64][72] overlay (q+k dead)
  unsigned short* xstage = lds + 4*5120;      // [2][64][32]

  // zero-seed rows 49..63 of both x buffers (never re-written)
  for (int i = threadIdx.x; i < 2*15*32; i += 256){
    int bf = i / 480, rem = i % 480;
    xstage[bf*2048 + (49 + rem/32)*32 + (rem & 31)] = 0;
  }

  const unsigned short* xwin = xb + (size_t)b*49*512;
  const int srow = wave*16 + (lane>>2);      // row this lane stages
  const int cbase = h * 32;
  const unsigned short* xsrc = xwin + (size_t)srow*512 + (lane&3)*8;

  // per-lane B pointers (ks*32 folded in as immediate after unroll)
  const unsigned short* bptr[6];
  #pragma unroll
  for (int wq=0; wq<3; ++wq)
    #pragma unroll
    for (int ct=0; ct<2; ++ct)
      bptr[wq*2+ct] = wqkv_t + (size_t)(wq*512 + cbase + ct*16 + l16)*512 + lg*8;

  __syncthreads();  // zero-seed visible
  if (srow < 49) gload_lds16(xsrc, xstage + wave*512);
  __syncthreads();  // tile 0 resident

  // ---- qkv GEMM: 64 tokens x (3 x 32) cols for head h ----
  f32x4 acc[3][4][2];
  #pragma unroll
  for (int a=0;a<3;++a)
    #pragma unroll
    for (int rt=0;rt<4;++rt)
      #pragma unroll
      for (int ct=0;ct<2;++ct)
        acc[a][rt][ct] = ZERO4;

  #pragma unroll 2
  for (int ks = 0; ks < 16; ++ks){
    const int p = ks & 1;

    // B-fragments first
    s16x8 bfrag[6];
    #pragma unroll
    for (int i=0;i<6;++i)
      bfrag[i] = *(const s16x8*)(bptr[i] + ks*32);

    // prefetch next x-tile last -> outstanding across the MFMAs
    if (ks < 15 && srow < 49)
      gload_lds16(xsrc + (ks+1)*32, xstage + ((ks+1)&1)*2048 + wave*512);

    s16x8 afrag[4];
    #pragma unroll
    for (int rt=0; rt<4; ++rt)
      afrag[rt] = *(const s16x8*)&xstage[p*2048 + (rt*16 + l16)*32 + lg*8];

    #pragma unroll
    for (int wq=0;wq<3;++wq)
      #pragma unroll
      for (int rt=0;rt<4;++rt)
        #pragma unroll
        for (int ct=0;ct<2;++ct)
          acc[wq][rt][ct] = MFMA16(afrag[rt], bfrag[wq*2+ct], acc[wq][rt][ct]);

    __syncthreads();  // reads of buf p done; stage(ks+1) drained
  }

  // ---- epilogue: q,k -> LDS (row-major); v -> packed bf16 registers ----
  uint2 vpk[4][2];   // [rt][ct]: V rows rt*16+lg*4..+3, col ct*16+l16 (bf16x4)
  #pragma unroll
  for (int wq=0; wq<3; ++wq){
    #pragma unroll
    for (int ct=0; ct<2; ++ct){
      const int c = wq*512 + cbase + ct*16 + l16;
      const float bv = bqkv_s[c];
      #pragma unroll
      for (int rt=0; rt<4; ++rt){
        f32x4 vv = acc[wq][rt][ct];
        const int row0 = rt*16 + lg*4;
        if (wq == 0){
          #pragma unroll
          for (int r=0;r<4;++r) q_lds[(row0+r)*40 + ct*16 + l16] = f2bf(vv[r]+bv);
        } else if (wq == 1){
          #pragma unroll
          for (int r=0;r<4;++r) k_lds[(row0+r)*40 + ct*16 + l16] = f2bf(vv[r]+bv);
        } else {
          uint2 pk;
          pk.x = (unsigned)f2bf(vv[0]+bv) | ((unsigned)f2bf(vv[1]+bv) << 16);
          pk.y = (unsigned)f2bf(vv[2]+bv) | ((unsigned)f2bf(vv[3]+bv) << 16);
          vpk[rt][ct] = pk;
        }
      }
    }
  }

  // ---- scores S = q @ k^T ----
  s16x8 aq[4], bk[4];
  #pragma unroll
  for (int t=0;t<4;++t){
    aq[t] = *(const s16x8*)&q_lds[(t*16+l16)*40 + lg*8];
    bk[t] = *(const s16x8*)&k_lds[(t*16+l16)*40 + lg*8];
  }
  f32x4 sacc[4][4];
  #pragma unroll
  for (int rt=0;rt<4;++rt)
    #pragma unroll
    for (int ct=0;ct<4;++ct)
      sacc[rt][ct] = MFMA16(aq[rt], bk[ct], ZERO4);

  // ---- softmax: bias (mask folded), batched 16-row reductions ----
  const float* biash = bias_t + (h << 12);
  float pm[4][4];
  #pragma unroll
  for (int rt=0;rt<4;++rt){
    #pragma unroll
    for (int r=0;r<4;++r){
      const int row = rt*16 + lg*4 + r;
      const float* brow = biash + (row << 6) + l16;
      float s0 = sacc[rt][0][r] + brow[0];
      float s1 = sacc[rt][1][r] + brow[16];
      float s2 = sacc[rt][2][r] + brow[32];
      float s3 = sacc[rt][3][r] + brow[48];
      sacc[rt][0][r]=s0; sacc[rt][1][r]=s1; sacc[rt][2][r]=s2; sacc[rt][3][r]=s3;
      pm[rt][r] = fmaxf(fmaxf(s0,s1), fmaxf(s2,s3));
    }
  }
  #pragma unroll
  for (int d=1; d<16; d<<=1)
    #pragma unroll
    for (int rt=0;rt<4;++rt)
      #pragma unroll
      for (int r=0;r<4;++r)
        pm[rt][r] = fmaxf(pm[rt][r], __shfl_xor(pm[rt][r], d));

  float ps[4][4];
  #pragma unroll
  for (int rt=0;rt<4;++rt){
    #pragma unroll
    for (int r=0;r<4;++r){
      const float m = pm[rt][r];
      float e0 = __expf(sacc[rt][0][r]-m), e1 = __expf(sacc[rt][1][r]-m);
      float e2 = __expf(sacc[rt][2][r]-m), e3 = __expf(sacc[rt][3][r]-m);
      sacc[rt][0][r]=e0; sacc[rt][1][r]=e1; sacc[rt][2][r]=e2; sacc[rt][3][r]=e3;
      ps[rt][r] = e0+e1+e2+e3;
    }
  }
  #pragma unroll
  for (int d=1; d<16; d<<=1)
    #pragma unroll
    for (int rt=0;rt<4;++rt)
      #pragma unroll
      for (int r=0;r<4;++r)
        ps[rt][r] += __shfl_xor(ps[rt][r], d);

  #pragma unroll
  for (int rt=0;rt<4;++rt){
    #pragma unroll
    for (int r=0;r<4;++r){
      const int row = rt*16 + lg*4 + r;
      const float inv = 1.f / ps[rt][r];
      p_lds[row*72 +      l16] = f2bf(sacc[rt][0][r]*inv);
      p_lds[row*72 + 16 + l16] = f2bf(sacc[rt][1][r]*inv);
      p_lds[row*72 + 32 + l16] = f2bf(sacc[rt][2][r]*inv);
      p_lds[row*72 + 48 + l16] = f2bf(sacc[rt][3][r]*inv);
    }
  }

  // ---- O = P @ v ;  V B-fragments via in-wave shuffles -------------------
  const int srcA = l16 + ((lg & 1) << 5);
  const int srcB = srcA + 16;
  const bool hiSel = (lg >> 1) != 0;

  f32x4 oacc[4][2];
  #pragma unroll
  for (int rt=0;rt<4;++rt)
    #pragma unroll
    for (int ct=0;ct<2;++ct)
      oacc[rt][ct] = ZERO4;

  #pragma unroll
  for (int kt=0; kt<2; ++kt){
    s16x8 ap[4], bv2[2];
    #pragma unroll
    for (int rt=0;rt<4;++rt)
      ap[rt] = *(const s16x8*)&p_lds[(rt*16+l16)*72 + kt*32 + lg*8];
    #pragma unroll
    for (int ct=0;ct<2;++ct){
      unsigned a0x = (unsigned)__shfl((int)vpk[2*kt  ][ct].x, srcA, 64);
      unsigned a0y = (unsigned)__shfl((int)vpk[2*kt  ][ct].y, srcA, 64);
      unsigned a1x = (unsigned)__shfl((int)vpk[2*kt+1][ct].x, srcA, 64);
      unsigned a1y = (unsigned)__shfl((int)vpk[2*kt+1][ct].y, srcA, 64);
      unsigned b0x = (unsigned)__shfl((int)vpk[2*kt  ][ct].x, srcB, 64);
      unsigned b0y = (unsigned)__shfl((int)vpk[2*kt  ][ct].y, srcB, 64);
      unsigned b1x = (unsigned)__shfl((int)vpk[2*kt+1][ct].x, srcB, 64);
      unsigned b1y = (unsigned)__shfl((int)vpk[2*kt+1][ct].y, srcB, 64);
      union { s16x8 v; unsigned u[4]; } fr;
      fr.u[0] = hiSel ? a1x : a0x;
      fr.u[1] = hiSel ? a1y : a0y;
      fr.u[2] = hiSel ? b1x : b0x;
      fr.u[3] = hiSel ? b1y : b0y;
      bv2[ct] = fr.v;
    }
    #pragma unroll
    for (int rt=0;rt<4;++rt)
      #pragma unroll
      for (int ct=0;ct<2;++ct)
        oacc[rt][ct] = MFMA16(ap[rt], bv2[ct], oacc[rt][ct]);
  }

  // ---- restage O through LDS for coalesced bf16 stores ----
  unsigned short* o_lds = p_lds;  // [64][40]
  #pragma unroll
  for (int rt=0;rt<4;++rt)
    #pragma unroll
    for (int ct=0;ct<2;++ct){
      const int row0 = rt*16 + lg*4;
      f32x4 vv = oacc[rt][ct];
      #pragma unroll
      for (int r=0;r<4;++r)
        o_lds[(row0+r)*40 + ct*16 + l16] = f2bf(vv[r]);
    }
  unsigned short* attb = att + (size_t)b*49*512 + h*32;
  for (int i = lane; i < 49*4; i += 64){
    const int row = i >> 2, seg = i & 3;
    *(s16x8*)&attb[(size_t)row*512 + seg*8] = *(const s16x8*)&o_lds[row*40 + seg*8];
  }
}

// ---------------- fallback (f32 x direct, small ws) ------------------------
__global__ __launch_bounds__(256, 2) void k_qkv_attn_f32(
    const float* __restrict__ x,
    const unsigned short* __restrict__ wqkv_t,
    const float* __restrict__ bqkv_s,
    const float* __restrict__ btab,
    unsigned short* __restrict__ att)
{
  __shared__ unsigned short lds[4*7424];
  const int lane = threadIdx.x & 63;
  const int wave = threadIdx.x >> 6;
  const int b    = blockIdx.x >> 2;
  const int h    = ((blockIdx.x & 3) << 2) | wave;
  const int l16  = lane & 15;
  const int lg   = lane >> 4;
  const f32x4 ZERO4 = {0.f, 0.f, 0.f, 0.f};

  unsigned short* q_lds = lds + wave*7424;
  unsigned short* k_lds = q_lds + 2560;
  unsigned short* vT    = q_lds + 5120;
  unsigned short* p_lds = q_lds;

  f32x4 acc[3][4][2];
  #pragma unroll
  for (int a=0;a<3;++a)
    #pragma unroll
    for (int rt=0;rt<4;++rt)
      #pragma unroll
      for (int ct=0;ct<2;++ct)
        acc[a][rt][ct] = ZERO4;

  const float* xbp = x + (size_t)b * 49 * 512;
  const int cbase = h * 32;

  #pragma unroll 2
  for (int ks = 0; ks < 16; ++ks){
    const int k0 = ks*32 + lg*8;
    s16x8 afrag[4];
    #pragma unroll
    for (int rt=0; rt<4; ++rt){
      const int n = rt*16 + l16;
      f32x4 v0 = ZERO4, v1 = ZERO4;
      if (n < 49){
        const float* p = xbp + n*512 + k0;
        v0 = *(const f32x4*)p;
        v1 = *(const f32x4*)(p + 4);
      }
      s16x8 t;
      t[0]=(short)f2bf(v0[0]); t[1]=(short)f2bf(v0[1]);
      t[2]=(short)f2bf(v0[2]); t[3]=(short)f2bf(v0[3]);
      t[4]=(short)f2bf(v1[0]); t[5]=(short)f2bf(v1[1]);
      t[6]=(short)f2bf(v1[2]); t[7]=(short)f2bf(v1[3]);
      afrag[rt] = t;
    }
    s16x8 bfrag[3][2];
    #pragma unroll
    for (int wq=0;wq<3;++wq)
      #pragma unroll
      for (int ct=0;ct<2;++ct){
        const int c = wq*512 + cbase + ct*16 + l16;
        bfrag[wq][ct] = *(const s16x8*)(wqkv_t + (size_t)c*512 + k0);
      }
    #pragma unroll
    for (int wq=0;wq<3;++wq)
      #pragma unroll
      for (int rt=0;rt<4;++rt)
        #pragma unroll
        for (int ct=0;ct<2;++ct)
          acc[wq][rt][ct] = MFMA16(afrag[rt], bfrag[wq][ct], acc[wq][rt][ct]);
  }

  #pragma unroll
  for (int wq=0; wq<3; ++wq){
    #pragma unroll
    for (int ct=0; ct<2; ++ct){
      const int c = wq*512 + cbase + ct*16 + l16;
      const float bv = bqkv_s[c];
      #pragma unroll
      for (int rt=0; rt<4; ++rt){
        f32x4 vv = acc[wq][rt][ct];
        const int row0 = rt*16 + lg*4;
        if (wq == 0){
          #pragma unroll
          for (int r=0;r<4;++r) q_lds[(row0+r)*40 + ct*16 + l16] = f2bf(vv[r]+bv);
        } else if (wq == 1){
          #pragma unroll
          for (int r=0;r<4;++r) k_lds[(row0+r)*40 + ct*16 + l16] = f2bf(vv[r]+bv);
        } else {
          ushort4 pk;
          pk.x=f2bf(vv[0]+bv); pk.y=f2bf(vv[1]+bv);
          pk.z=f2bf(vv[2]+bv); pk.w=f2bf(vv[3]+bv);
          *(ushort4*)&vT[(ct*16+l16)*72 + row0] = pk;
        }
      }
    }
  }

  s16x8 aq[4], bk[4];
  #pragma unroll
  for (int t=0;t<4;++t){
    aq[t] = *(const s16x8*)&q_lds[(t*16+l16)*40 + lg*8];
    bk[t] = *(const s16x8*)&k_lds[(t*16+l16)*40 + lg*8];
  }
  f32x4 sacc[4][4];
  #pragma unroll
  for (int rt=0;rt<4;++rt)
    #pragma unroll
    for (int ct=0;ct<4;++ct)
      sacc[rt][ct] = MFMA16(aq[rt], bk[ct], ZERO4);

  int colv[4], kyv[4], kxv[4];
  #pragma unroll
  for (int ct=0;ct<4;++ct){
    colv[ct] = ct*16 + l16;
    kyv[ct]  = colv[ct] / 7;
    kxv[ct]  = colv[ct] % 7;
  }
  #pragma unroll
  for (int rt=0;rt<4;++rt){
    #pragma unroll
    for (int r=0;r<4;++r){
      const int row = rt*16 + lg*4 + r;
      const int qy = row / 7, qx = row % 7;
      float sv[4];
      #pragma unroll
      for (int ct=0;ct<4;++ct){
        float s = sacc[rt][ct][r];
        if (row < 49 && colv[ct] < 49){
          const int idx = (qy - kyv[ct] + 6)*13 + (qx - kxv[ct] + 6);
          s += btab[idx*16 + h];
        }
        if (colv[ct] >= 49) s = -1e30f;
        else if (row >= 49) s = 0.f;
        sv[ct] = s;
      }
      float m = fmaxf(fmaxf(sv[0],sv[1]), fmaxf(sv[2],sv[3]));
      #pragma unroll
      for (int d=1; d<16; d<<=1) m = fmaxf(m, __shfl_xor(m, d));
      float e0 = __expf(sv[0]-m), e1 = __expf(sv[1]-m);
      float e2 = __expf(sv[2]-m), e3 = __expf(sv[3]-m);
      float sum = e0+e1+e2+e3;
      #pragma unroll
      for (int d=1; d<16; d<<=1) sum += __shfl_xor(sum, d);
      const float inv = 1.f / sum;
      p_lds[row*72 + colv[0]] = f2bf(e0*inv);
      p_lds[row*72 + colv[1]] = f2bf(e1*inv);
      p_lds[row*72 + colv[2]] = f2bf(e2*inv);
      p_lds[row*72 + colv[3]] = f2bf(e3*inv);
    }
  }

  f32x4 oacc[4][2];
  #pragma unroll
  for (int rt=0;rt<4;++rt)
    #pragma unroll
    for (int ct=0;ct<2;++ct)
      oacc[rt][ct] = ZERO4;
  #pragma unroll
  for (int kt=0; kt<2; ++kt){
    s16x8 ap[4], bv2[2];
    #pragma unroll
    for (int rt=0;rt<4;++rt)
      ap[rt] = *(const s16x8*)&p_lds[(rt*16+l16)*72 + kt*32 + lg*8];
    #pragma unroll
    for (int ct=0;ct<2;++ct)
      bv2[ct] = *(const s16x8*)&vT[(ct*16+l16)*72 + kt*32 + lg*8];
    #pragma unroll
    for (int rt=0;rt<4;++rt)
      #pragma unroll
      for (int ct=0;ct<2;++ct)
        oacc[rt][ct] = MFMA16(ap[rt], bv2[ct], oacc[rt][ct]);
  }

  unsigned short* o_lds = p_lds;
  #pragma unroll
  for (int rt=0;rt<4;++rt)
    #pragma unroll
    for (int ct=0;ct<2;++ct){
      const int row0 = rt*16 + lg*4;
      f32x4 vv = oacc[rt][ct];
      #pragma unroll
      for (int r=0;r<4;++r)
        o_lds[(row0+r)*40 + ct*16 + l16] = f2bf(vv[r]);
    }
  unsigned short* attb = att + (size_t)b*49*512 + h*32;
  for (int i = lane; i < 49*4; i += 64){
    const int row = i >> 2, seg = i & 3;
    *(s16x8*)&attb[(size_t)row*512 + seg*8] = *(const s16x8*)&o_lds[row*40 + seg*8];
  }
}

// ---------------- proj GEMM: out = att(bf16) @ proj_w + b, fp32 out --------
__global__ __launch_bounds__(256) void k_proj(
    const unsigned short* __restrict__ att,    // (50176,512) bf16
    const unsigned short* __restrict__ wproj_t,// (512,512) bf16, [c][k]
    const float* __restrict__ proj_b,          // (512)
    float* __restrict__ out)                   // (50176,512) f32
{
  const int lane = threadIdx.x & 63;
  const int wave = threadIdx.x >> 6;
  const int l16  = lane & 15;
  const int lg   = lane >> 4;
  const int mb = blockIdx.x >> 2;
  const int nb = blockIdx.x & 3;
  const int m0 = mb*128 + (wave>>1)*64;
  const int n0 = nb*128 + (wave&1)*64;
  const f32x4 ZERO4 = {0.f, 0.f, 0.f, 0.f};

  f32x4 acc[4][4];
  #pragma unroll
  for (int rt=0;rt<4;++rt)
    #pragma unroll
    for (int ct=0;ct<4;++ct)
      acc[rt][ct] = ZERO4;

  #pragma unroll 2
  for (int ks=0; ks<16; ++ks){
    const int k0 = ks*32 + lg*8;
    s16x8 a[4], bw[4];
    #pragma unroll
    for (int t=0;t<4;++t){
      a[t]  = *(const s16x8*)(att     + (size_t)(m0 + t*16 + l16)*512 + k0);
      bw[t] = *(const s16x8*)(wproj_t + (size_t)(n0 + t*16 + l16)*512 + k0);
    }
    #pragma unroll
    for (int rt=0;rt<4;++rt)
      #pragma unroll
      for (int ct=0;ct<4;++ct)
        acc[rt][ct] = MFMA16(a[rt], bw[ct], acc[rt][ct]);
  }

  #pragma unroll
  for (int ct=0;ct<4;++ct){
    const float bv = proj_b[n0 + ct*16 + l16];
    #pragma unroll
    for (int rt=0;rt<4;++rt){
      const int row = m0 + rt*16 + lg*4;
      #pragma unroll
      for (int r=0;r<4;++r)
        out[(size_t)(row+r)*512 + n0 + ct*16 + l16] = acc[rt][ct][r] + bv;
    }
  }
}

// ---------------- launcher -------------------------------------------------
extern "C" void kernel_launch(void* const* d_in, const int* in_sizes, int n_in,
                              void* d_out, int out_size, void* d_ws, size_t ws_size,
                              hipStream_t stream)
{
  const float* x      = (const float*)d_in[0];
  const float* qkv_w  = (const float*)d_in[1];
  const float* qkv_b  = (const float*)d_in[2];
  const float* btab   = (const float*)d_in[3];
  const float* proj_w = (const float*)d_in[4];
  const float* proj_b = (const float*)d_in[5];
  float* out = (float*)d_out;

  char* ws = (char*)d_ws;
  const size_t ATT = 51380224ULL;   // 50176*512*2
  const size_t XB  = 51380224ULL;
  const size_t WQ  = 1572864ULL;
  const size_t WP  = 524288ULL;
  const size_t BT  = 262144ULL;     // 16*64*64*4
  const size_t need_big = ATT + XB + WQ + WP + BT + 8192;

  if (ws_size >= need_big){
    unsigned short* att     = (unsigned short*)ws;
    unsigned short* xbb     = (unsigned short*)(ws + ATT);
    unsigned short* wqkv_t  = (unsigned short*)(ws + ATT + XB);
    unsigned short* wproj_t = (unsigned short*)(ws + ATT + XB + WQ);
    float*          bias_t  = (float*)(ws + ATT + XB + WQ + WP);
    float*          bqkv_s  = (float*)(ws + ATT + XB + WQ + WP + BT);

    k_prep2<<<12544 + 512, 256, 0, stream>>>(x, qkv_w, qkv_b, proj_w, btab,
                                             xbb, wqkv_t, wproj_t, bqkv_s, bias_t);
    k_qkv_attn7<<<1024*4, 256, 0, stream>>>(xbb, wqkv_t, bqkv_s, bias_t, att);
    k_proj<<<392*4, 256, 0, stream>>>(att, wproj_t, proj_b, out);
  } else {
    unsigned short* att     = (unsigned short*)ws;
    unsigned short* wqkv_t  = (unsigned short*)(ws + ATT);
    unsigned short* wproj_t = (unsigned short*)(ws + ATT + WQ);
    float*          bqkv_s  = (float*)(ws + ATT + WQ + WP);

    k_prep2<<<12544 + 512, 256, 0, stream>>>(x, qkv_w, qkv_b, proj_w, btab,
                                             att /*scratch, overwritten later*/,
                                             wqkv_t, wproj_t, bqkv_s,
                                             (float*)(ws + ATT + WQ + WP + 8192));
    k_qkv_attn_f32<<<1024*4, 256, 0, stream>>>(x, wqkv_t, bqkv_s, btab, att);
    k_proj<<<392*4, 256, 0, stream>>>(att, wproj_t, proj_b, out);
  }
}

// Round 9
// 347.743 us; speedup vs baseline: 1.2372x; 1.0304x over previous
//
#include <hip/hip_runtime.h>
#include <hip/hip_bf16.h>

typedef __attribute__((ext_vector_type(4))) float f32x4;
typedef __attribute__((ext_vector_type(8))) short s16x8;

#define MFMA16(a,b,c) __builtin_amdgcn_mfma_f32_16x16x32_bf16(a,b,c,0,0,0)

__device__ __forceinline__ unsigned short f2bf(float f){
  __hip_bfloat16 h = __float2bfloat16(f);
  return *reinterpret_cast<unsigned short*>(&h);
}

__device__ __forceinline__ void gload_lds16(const unsigned short* g, unsigned short* l){
  __builtin_amdgcn_global_load_lds(
      (const __attribute__((address_space(1))) unsigned int*)(const void*)g,
      (__attribute__((address_space(3))) unsigned int*)(void*)l,
      16, 0, 0);
}

// ---------------- fused x->bf16 cast + weight prep -------------------------
__global__ void k_prep2(const float* __restrict__ x,
                        const float* __restrict__ qkv_w,   // (512,1536)
                        const float* __restrict__ qkv_b,   // (1536)
                        const float* __restrict__ proj_w,  // (512,512)
                        const float* __restrict__ btab,    // (169,16)
                        unsigned short* __restrict__ xb,      // (50176,512) bf16
                        unsigned short* __restrict__ wqkv_t,  // (1536,512) bf16
                        unsigned short* __restrict__ wproj_t, // (512,512) bf16
                        float* __restrict__ bqkv_s,           // (1536) f32
                        float* __restrict__ bias_t)           // (16,64,64) f32
{
  if (blockIdx.x < 12544){
    const int i = blockIdx.x * 256 + threadIdx.x;   // one 8-elem chunk
    const float* p = x + (size_t)i*8;
    f32x4 v0 = *(const f32x4*)p, v1 = *(const f32x4*)(p+4);
    s16x8 t;
    t[0]=(short)f2bf(v0[0]); t[1]=(short)f2bf(v0[1]);
    t[2]=(short)f2bf(v0[2]); t[3]=(short)f2bf(v0[3]);
    t[4]=(short)f2bf(v1[0]); t[5]=(short)f2bf(v1[1]);
    t[6]=(short)f2bf(v1[2]); t[7]=(short)f2bf(v1[3]);
    *(s16x8*)(xb + (size_t)i*8) = t;
    return;
  }
  const float scale = 0.17677669529663687f; // 32^-0.5
  int tid = (blockIdx.x - 12544) * 256 + threadIdx.x;
  int np  = 512 * 256;
  for (int i = tid; i < 1536*512; i += np){
    int c = i >> 9, k = i & 511;
    float w = qkv_w[k*1536 + c];
    if (c < 512) w *= scale;
    wqkv_t[i] = f2bf(w);
  }
  for (int i = tid; i < 512*512; i += np){
    int c = i >> 9, k = i & 511;
    wproj_t[i] = f2bf(proj_w[k*512 + c]);
  }
  for (int i = tid; i < 1536; i += np){
    float bv = qkv_b[i];
    if (i < 512) bv *= scale;
    bqkv_s[i] = bv;
  }
  for (int i = tid; i < 16*64*64; i += np){
    int hh = i >> 12, rc = i & 4095, row = rc >> 6, col = rc & 63;
    float v;
    if (col >= 49)      v = -1e30f;
    else if (row >= 49) v = 0.f;
    else {
      int qy = row/7, qx = row%7, ky = col/7, kx = col%7;
      v = btab[((qy-ky+6)*13 + (qx-kx+6))*16 + hh];
    }
    bias_t[i] = v;
  }
}

// ---------------- fused qkv GEMM + window attention ------------------------
// grid: 4096 blocks (= 8 XCDs x 4 head-groups x 128 window-blocks), XCD-swizzled
// so the 4 head-group siblings of a window land on the SAME XCD (shared x in L2).
// LDS: per-wave q[64][40]+k[64][40] = 5120 shorts (P[64][72] overlays)
//      + shared x dbuf [2][64][32] = 4096 shorts. Block = 49152 B -> 3/CU.
__global__ __launch_bounds__(256, 3) void k_qkv_attn8(
    const unsigned short* __restrict__ xb,    // (50176,512) bf16
    const unsigned short* __restrict__ wqkv_t,// (1536,512) bf16 (q pre-scaled)
    const float* __restrict__ bqkv_s,         // (1536) f32 (q pre-scaled)
    const float* __restrict__ bias_t,         // (16,64,64) f32, mask folded
    unsigned short* __restrict__ att)         // (1024,49,512) bf16
{
  __shared__ unsigned short lds[4*5120 + 2*2048];
  const int lane = threadIdx.x & 63;
  const int wave = threadIdx.x >> 6;
  // XCD-bijective decode: bid = xcd + 8*(g + 4*wblk); window b = xcd + 8*wblk
  const int bid  = blockIdx.x;
  const int xcd  = bid & 7;
  const int g    = (bid >> 3) & 3;
  const int wblk = bid >> 5;
  const int b    = xcd + (wblk << 3);
  const int h    = (g << 2) | wave;
  const int l16  = lane & 15;
  const int lg   = lane >> 4;   // 0..3
  const f32x4 ZERO4 = {0.f, 0.f, 0.f, 0.f};

  unsigned short* q_lds  = lds + wave*5120;   // [64][40]
  unsigned short* k_lds  = q_lds + 2560;      // [64][40]
  unsigned short* p_lds  = q_lds;             // [64][72] overlay (q+k dead)
  unsigned short* xstage = lds + 4*5120;      // [2][64][32]

  // zero-seed rows 49..63 of both x buffers (never re-written)
  for (int i = threadIdx.x; i < 2*15*32; i += 256){
    int bf = i / 480, rem = i % 480;
    xstage[bf*2048 + (49 + rem/32)*32 + (rem & 31)] = 0;
  }

  const unsigned short* xwin = xb + (size_t)b*49*512;
  const int srow = wave*16 + (lane>>2);      // row this lane stages
  const int cbase = h * 32;
  const unsigned short* xsrc = xwin + (size_t)srow*512 + (lane&3)*8;

  // single per-lane B base; (wq,ct) offsets are uniform compile-time consts
  const unsigned short* bbase =
      wqkv_t + (size_t)(cbase + l16)*512 + lg*8;

  __syncthreads();  // zero-seed visible
  if (srow < 49) gload_lds16(xsrc, xstage + wave*512);
  __syncthreads();  // tile 0 resident

  // ---- qkv GEMM: 64 tokens x (3 x 32) cols for head h ----
  f32x4 acc[3][4][2];
  #pragma unroll
  for (int a=0;a<3;++a)
    #pragma unroll
    for (int rt=0;rt<4;++rt)
      #pragma unroll
      for (int ct=0;ct<2;++ct)
        acc[a][rt][ct] = ZERO4;

  #pragma unroll 2
  for (int ks = 0; ks < 16; ++ks){
    const int p = ks & 1;

    // B-fragments first (uniform offsets: wq*512*512 + ct*16*512 elements)
    s16x8 bfrag[6];
    #pragma unroll
    for (int wq=0; wq<3; ++wq)
      #pragma unroll
      for (int ct=0; ct<2; ++ct)
        bfrag[wq*2+ct] = *(const s16x8*)(bbase + wq*262144 + ct*8192 + ks*32);

    // prefetch next x-tile last -> outstanding across the MFMAs
    if (ks < 15 && srow < 49)
      gload_lds16(xsrc + (ks+1)*32, xstage + ((ks+1)&1)*2048 + wave*512);

    s16x8 afrag[4];
    #pragma unroll
    for (int rt=0; rt<4; ++rt)
      afrag[rt] = *(const s16x8*)&xstage[p*2048 + (rt*16 + l16)*32 + lg*8];

    #pragma unroll
    for (int wq=0;wq<3;++wq)
      #pragma unroll
      for (int rt=0;rt<4;++rt)
        #pragma unroll
        for (int ct=0;ct<2;++ct)
          acc[wq][rt][ct] = MFMA16(afrag[rt], bfrag[wq*2+ct], acc[wq][rt][ct]);

    __syncthreads();  // reads of buf p done; stage(ks+1) drained
  }

  // ---- epilogue: q,k -> LDS (row-major); v -> packed bf16 registers ----
  uint2 vpk[4][2];   // [rt][ct]: V rows rt*16+lg*4..+3, col ct*16+l16 (bf16x4)
  #pragma unroll
  for (int wq=0; wq<3; ++wq){
    #pragma unroll
    for (int ct=0; ct<2; ++ct){
      const int c = wq*512 + cbase + ct*16 + l16;
      const float bv = bqkv_s[c];
      #pragma unroll
      for (int rt=0; rt<4; ++rt){
        f32x4 vv = acc[wq][rt][ct];
        const int row0 = rt*16 + lg*4;
        if (wq == 0){
          #pragma unroll
          for (int r=0;r<4;++r) q_lds[(row0+r)*40 + ct*16 + l16] = f2bf(vv[r]+bv);
        } else if (wq == 1){
          #pragma unroll
          for (int r=0;r<4;++r) k_lds[(row0+r)*40 + ct*16 + l16] = f2bf(vv[r]+bv);
        } else {
          uint2 pk;
          pk.x = (unsigned)f2bf(vv[0]+bv) | ((unsigned)f2bf(vv[1]+bv) << 16);
          pk.y = (unsigned)f2bf(vv[2]+bv) | ((unsigned)f2bf(vv[3]+bv) << 16);
          vpk[rt][ct] = pk;
        }
      }
    }
  }

  // ---- scores S = q @ k^T ----
  s16x8 aq[4], bk[4];
  #pragma unroll
  for (int t=0;t<4;++t){
    aq[t] = *(const s16x8*)&q_lds[(t*16+l16)*40 + lg*8];
    bk[t] = *(const s16x8*)&k_lds[(t*16+l16)*40 + lg*8];
  }
  f32x4 sacc[4][4];
  #pragma unroll
  for (int rt=0;rt<4;++rt)
    #pragma unroll
    for (int ct=0;ct<4;++ct)
      sacc[rt][ct] = MFMA16(aq[rt], bk[ct], ZERO4);

  // ---- softmax: bias (mask folded), batched 16-row reductions ----
  const float* biash = bias_t + (h << 12);
  float pm[4][4];
  #pragma unroll
  for (int rt=0;rt<4;++rt){
    #pragma unroll
    for (int r=0;r<4;++r){
      const int row = rt*16 + lg*4 + r;
      const float* brow = biash + (row << 6) + l16;
      float s0 = sacc[rt][0][r] + brow[0];
      float s1 = sacc[rt][1][r] + brow[16];
      float s2 = sacc[rt][2][r] + brow[32];
      float s3 = sacc[rt][3][r] + brow[48];
      sacc[rt][0][r]=s0; sacc[rt][1][r]=s1; sacc[rt][2][r]=s2; sacc[rt][3][r]=s3;
      pm[rt][r] = fmaxf(fmaxf(s0,s1), fmaxf(s2,s3));
    }
  }
  #pragma unroll
  for (int d=1; d<16; d<<=1)
    #pragma unroll
    for (int rt=0;rt<4;++rt)
      #pragma unroll
      for (int r=0;r<4;++r)
        pm[rt][r] = fmaxf(pm[rt][r], __shfl_xor(pm[rt][r], d));

  float ps[4][4];
  #pragma unroll
  for (int rt=0;rt<4;++rt){
    #pragma unroll
    for (int r=0;r<4;++r){
      const float m = pm[rt][r];
      float e0 = __expf(sacc[rt][0][r]-m), e1 = __expf(sacc[rt][1][r]-m);
      float e2 = __expf(sacc[rt][2][r]-m), e3 = __expf(sacc[rt][3][r]-m);
      sacc[rt][0][r]=e0; sacc[rt][1][r]=e1; sacc[rt][2][r]=e2; sacc[rt][3][r]=e3;
      ps[rt][r] = e0+e1+e2+e3;
    }
  }
  #pragma unroll
  for (int d=1; d<16; d<<=1)
    #pragma unroll
    for (int rt=0;rt<4;++rt)
      #pragma unroll
      for (int r=0;r<4;++r)
        ps[rt][r] += __shfl_xor(ps[rt][r], d);

  #pragma unroll
  for (int rt=0;rt<4;++rt){
    #pragma unroll
    for (int r=0;r<4;++r){
      const int row = rt*16 + lg*4 + r;
      const float inv = 1.f / ps[rt][r];
      p_lds[row*72 +      l16] = f2bf(sacc[rt][0][r]*inv);
      p_lds[row*72 + 16 + l16] = f2bf(sacc[rt][1][r]*inv);
      p_lds[row*72 + 32 + l16] = f2bf(sacc[rt][2][r]*inv);
      p_lds[row*72 + 48 + l16] = f2bf(sacc[rt][3][r]*inv);
    }
  }

  // ---- O = P @ v ;  V B-fragments via in-wave shuffles -------------------
  const int srcA = l16 + ((lg & 1) << 5);
  const int srcB = srcA + 16;
  const bool hiSel = (lg >> 1) != 0;

  f32x4 oacc[4][2];
  #pragma unroll
  for (int rt=0;rt<4;++rt)
    #pragma unroll
    for (int ct=0;ct<2;++ct)
      oacc[rt][ct] = ZERO4;

  #pragma unroll
  for (int kt=0; kt<2; ++kt){
    s16x8 ap[4], bv2[2];
    #pragma unroll
    for (int rt=0;rt<4;++rt)
      ap[rt] = *(const s16x8*)&p_lds[(rt*16+l16)*72 + kt*32 + lg*8];
    #pragma unroll
    for (int ct=0;ct<2;++ct){
      unsigned a0x = (unsigned)__shfl((int)vpk[2*kt  ][ct].x, srcA, 64);
      unsigned a0y = (unsigned)__shfl((int)vpk[2*kt  ][ct].y, srcA, 64);
      unsigned a1x = (unsigned)__shfl((int)vpk[2*kt+1][ct].x, srcA, 64);
      unsigned a1y = (unsigned)__shfl((int)vpk[2*kt+1][ct].y, srcA, 64);
      unsigned b0x = (unsigned)__shfl((int)vpk[2*kt  ][ct].x, srcB, 64);
      unsigned b0y = (unsigned)__shfl((int)vpk[2*kt  ][ct].y, srcB, 64);
      unsigned b1x = (unsigned)__shfl((int)vpk[2*kt+1][ct].x, srcB, 64);
      unsigned b1y = (unsigned)__shfl((int)vpk[2*kt+1][ct].y, srcB, 64);
      union { s16x8 v; unsigned u[4]; } fr;
      fr.u[0] = hiSel ? a1x : a0x;
      fr.u[1] = hiSel ? a1y : a0y;
      fr.u[2] = hiSel ? b1x : b0x;
      fr.u[3] = hiSel ? b1y : b0y;
      bv2[ct] = fr.v;
    }
    #pragma unroll
    for (int rt=0;rt<4;++rt)
      #pragma unroll
      for (int ct=0;ct<2;++ct)
        oacc[rt][ct] = MFMA16(ap[rt], bv2[ct], oacc[rt][ct]);
  }

  // ---- restage O through LDS for coalesced bf16 stores ----
  unsigned short* o_lds = p_lds;  // [64][40]
  #pragma unroll
  for (int rt=0;rt<4;++rt)
    #pragma unroll
    for (int ct=0;ct<2;++ct){
      const int row0 = rt*16 + lg*4;
      f32x4 vv = oacc[rt][ct];
      #pragma unroll
      for (int r=0;r<4;++r)
        o_lds[(row0+r)*40 + ct*16 + l16] = f2bf(vv[r]);
    }
  unsigned short* attb = att + (size_t)b*49*512 + h*32;
  for (int i = lane; i < 49*4; i += 64){
    const int row = i >> 2, seg = i & 3;
    *(s16x8*)&attb[(size_t)row*512 + seg*8] = *(const s16x8*)&o_lds[row*40 + seg*8];
  }
}

// ---------------- fallback (f32 x direct, small ws) ------------------------
__global__ __launch_bounds__(256, 2) void k_qkv_attn_f32(
    const float* __restrict__ x,
    const unsigned short* __restrict__ wqkv_t,
    const float* __restrict__ bqkv_s,
    const float* __restrict__ btab,
    unsigned short* __restrict__ att)
{
  __shared__ unsigned short lds[4*7424];
  const int lane = threadIdx.x & 63;
  const int wave = threadIdx.x >> 6;
  const int b    = blockIdx.x >> 2;
  const int h    = ((blockIdx.x & 3) << 2) | wave;
  const int l16  = lane & 15;
  const int lg   = lane >> 4;
  const f32x4 ZERO4 = {0.f, 0.f, 0.f, 0.f};

  unsigned short* q_lds = lds + wave*7424;
  unsigned short* k_lds = q_lds + 2560;
  unsigned short* vT    = q_lds + 5120;
  unsigned short* p_lds = q_lds;

  f32x4 acc[3][4][2];
  #pragma unroll
  for (int a=0;a<3;++a)
    #pragma unroll
    for (int rt=0;rt<4;++rt)
      #pragma unroll
      for (int ct=0;ct<2;++ct)
        acc[a][rt][ct] = ZERO4;

  const float* xbp = x + (size_t)b * 49 * 512;
  const int cbase = h * 32;

  #pragma unroll 2
  for (int ks = 0; ks < 16; ++ks){
    const int k0 = ks*32 + lg*8;
    s16x8 afrag[4];
    #pragma unroll
    for (int rt=0; rt<4; ++rt){
      const int n = rt*16 + l16;
      f32x4 v0 = ZERO4, v1 = ZERO4;
      if (n < 49){
        const float* p = xbp + n*512 + k0;
        v0 = *(const f32x4*)p;
        v1 = *(const f32x4*)(p + 4);
      }
      s16x8 t;
      t[0]=(short)f2bf(v0[0]); t[1]=(short)f2bf(v0[1]);
      t[2]=(short)f2bf(v0[2]); t[3]=(short)f2bf(v0[3]);
      t[4]=(short)f2bf(v1[0]); t[5]=(short)f2bf(v1[1]);
      t[6]=(short)f2bf(v1[2]); t[7]=(short)f2bf(v1[3]);
      afrag[rt] = t;
    }
    s16x8 bfrag[3][2];
    #pragma unroll
    for (int wq=0;wq<3;++wq)
      #pragma unroll
      for (int ct=0;ct<2;++ct){
        const int c = wq*512 + cbase + ct*16 + l16;
        bfrag[wq][ct] = *(const s16x8*)(wqkv_t + (size_t)c*512 + k0);
      }
    #pragma unroll
    for (int wq=0;wq<3;++wq)
      #pragma unroll
      for (int rt=0;rt<4;++rt)
        #pragma unroll
        for (int ct=0;ct<2;++ct)
          acc[wq][rt][ct] = MFMA16(afrag[rt], bfrag[wq][ct], acc[wq][rt][ct]);
  }

  #pragma unroll
  for (int wq=0; wq<3; ++wq){
    #pragma unroll
    for (int ct=0; ct<2; ++ct){
      const int c = wq*512 + cbase + ct*16 + l16;
      const float bv = bqkv_s[c];
      #pragma unroll
      for (int rt=0; rt<4; ++rt){
        f32x4 vv = acc[wq][rt][ct];
        const int row0 = rt*16 + lg*4;
        if (wq == 0){
          #pragma unroll
          for (int r=0;r<4;++r) q_lds[(row0+r)*40 + ct*16 + l16] = f2bf(vv[r]+bv);
        } else if (wq == 1){
          #pragma unroll
          for (int r=0;r<4;++r) k_lds[(row0+r)*40 + ct*16 + l16] = f2bf(vv[r]+bv);
        } else {
          ushort4 pk;
          pk.x=f2bf(vv[0]+bv); pk.y=f2bf(vv[1]+bv);
          pk.z=f2bf(vv[2]+bv); pk.w=f2bf(vv[3]+bv);
          *(ushort4*)&vT[(ct*16+l16)*72 + row0] = pk;
        }
      }
    }
  }

  s16x8 aq[4], bk[4];
  #pragma unroll
  for (int t=0;t<4;++t){
    aq[t] = *(const s16x8*)&q_lds[(t*16+l16)*40 + lg*8];
    bk[t] = *(const s16x8*)&k_lds[(t*16+l16)*40 + lg*8];
  }
  f32x4 sacc[4][4];
  #pragma unroll
  for (int rt=0;rt<4;++rt)
    #pragma unroll
    for (int ct=0;ct<4;++ct)
      sacc[rt][ct] = MFMA16(aq[rt], bk[ct], ZERO4);

  int colv[4], kyv[4], kxv[4];
  #pragma unroll
  for (int ct=0;ct<4;++ct){
    colv[ct] = ct*16 + l16;
    kyv[ct]  = colv[ct] / 7;
    kxv[ct]  = colv[ct] % 7;
  }
  #pragma unroll
  for (int rt=0;rt<4;++rt){
    #pragma unroll
    for (int r=0;r<4;++r){
      const int row = rt*16 + lg*4 + r;
      const int qy = row / 7, qx = row % 7;
      float sv[4];
      #pragma unroll
      for (int ct=0;ct<4;++ct){
        float s = sacc[rt][ct][r];
        if (row < 49 && colv[ct] < 49){
          const int idx = (qy - kyv[ct] + 6)*13 + (qx - kxv[ct] + 6);
          s += btab[idx*16 + h];
        }
        if (colv[ct] >= 49) s = -1e30f;
        else if (row >= 49) s = 0.f;
        sv[ct] = s;
      }
      float m = fmaxf(fmaxf(sv[0],sv[1]), fmaxf(sv[2],sv[3]));
      #pragma unroll
      for (int d=1; d<16; d<<=1) m = fmaxf(m, __shfl_xor(m, d));
      float e0 = __expf(sv[0]-m), e1 = __expf(sv[1]-m);
      float e2 = __expf(sv[2]-m), e3 = __expf(sv[3]-m);
      float sum = e0+e1+e2+e3;
      #pragma unroll
      for (int d=1; d<16; d<<=1) sum += __shfl_xor(sum, d);
      const float inv = 1.f / sum;
      p_lds[row*72 + colv[0]] = f2bf(e0*inv);
      p_lds[row*72 + colv[1]] = f2bf(e1*inv);
      p_lds[row*72 + colv[2]] = f2bf(e2*inv);
      p_lds[row*72 + colv[3]] = f2bf(e3*inv);
    }
  }

  f32x4 oacc[4][2];
  #pragma unroll
  for (int rt=0;rt<4;++rt)
    #pragma unroll
    for (int ct=0;ct<2;++ct)
      oacc[rt][ct] = ZERO4;
  #pragma unroll
  for (int kt=0; kt<2; ++kt){
    s16x8 ap[4], bv2[2];
    #pragma unroll
    for (int rt=0;rt<4;++rt)
      ap[rt] = *(const s16x8*)&p_lds[(rt*16+l16)*72 + kt*32 + lg*8];
    #pragma unroll
    for (int ct=0;ct<2;++ct)
      bv2[ct] = *(const s16x8*)&vT[(ct*16+l16)*72 + kt*32 + lg*8];
    #pragma unroll
    for (int rt=0;rt<4;++rt)
      #pragma unroll
      for (int ct=0;ct<2;++ct)
        oacc[rt][ct] = MFMA16(ap[rt], bv2[ct], oacc[rt][ct]);
  }

  unsigned short* o_lds = p_lds;
  #pragma unroll
  for (int rt=0;rt<4;++rt)
    #pragma unroll
    for (int ct=0;ct<2;++ct){
      const int row0 = rt*16 + lg*4;
      f32x4 vv = oacc[rt][ct];
      #pragma unroll
      for (int r=0;r<4;++r)
        o_lds[(row0+r)*40 + ct*16 + l16] = f2bf(vv[r]);
    }
  unsigned short* attb = att + (size_t)b*49*512 + h*32;
  for (int i = lane; i < 49*4; i += 64){
    const int row = i >> 2, seg = i & 3;
    *(s16x8*)&attb[(size_t)row*512 + seg*8] = *(const s16x8*)&o_lds[row*40 + seg*8];
  }
}

// ---------------- proj GEMM: out = att(bf16) @ proj_w + b, fp32 out --------
// grid 1568 = 8 XCDs x (4 nb x 49 mgrp); swizzled so nb siblings share an XCD.
__global__ __launch_bounds__(256) void k_proj(
    const unsigned short* __restrict__ att,    // (50176,512) bf16
    const unsigned short* __restrict__ wproj_t,// (512,512) bf16, [c][k]
    const float* __restrict__ proj_b,          // (512)
    float* __restrict__ out)                   // (50176,512) f32
{
  const int lane = threadIdx.x & 63;
  const int wave = threadIdx.x >> 6;
  const int l16  = lane & 15;
  const int lg   = lane >> 4;
  const int bid  = blockIdx.x;
  const int xcd  = bid & 7;
  const int nb   = (bid >> 3) & 3;
  const int mgrp = bid >> 5;            // 0..48
  const int mb   = xcd + (mgrp << 3);   // 0..391
  const int m0 = mb*128 + (wave>>1)*64;
  const int n0 = nb*128 + (wave&1)*64;
  const f32x4 ZERO4 = {0.f, 0.f, 0.f, 0.f};

  f32x4 acc[4][4];
  #pragma unroll
  for (int rt=0;rt<4;++rt)
    #pragma unroll
    for (int ct=0;ct<4;++ct)
      acc[rt][ct] = ZERO4;

  #pragma unroll 2
  for (int ks=0; ks<16; ++ks){
    const int k0 = ks*32 + lg*8;
    s16x8 a[4], bw[4];
    #pragma unroll
    for (int t=0;t<4;++t){
      a[t]  = *(const s16x8*)(att     + (size_t)(m0 + t*16 + l16)*512 + k0);
      bw[t] = *(const s16x8*)(wproj_t + (size_t)(n0 + t*16 + l16)*512 + k0);
    }
    #pragma unroll
    for (int rt=0;rt<4;++rt)
      #pragma unroll
      for (int ct=0;ct<4;++ct)
        acc[rt][ct] = MFMA16(a[rt], bw[ct], acc[rt][ct]);
  }

  #pragma unroll
  for (int ct=0;ct<4;++ct){
    const float bv = proj_b[n0 + ct*16 + l16];
    #pragma unroll
    for (int rt=0;rt<4;++rt){
      const int row = m0 + rt*16 + lg*4;
      #pragma unroll
      for (int r=0;r<4;++r)
        out[(size_t)(row+r)*512 + n0 + ct*16 + l16] = acc[rt][ct][r] + bv;
    }
  }
}

// ---------------- launcher -------------------------------------------------
extern "C" void kernel_launch(void* const* d_in, const int* in_sizes, int n_in,
                              void* d_out, int out_size, void* d_ws, size_t ws_size,
                              hipStream_t stream)
{
  const float* x      = (const float*)d_in[0];
  const float* qkv_w  = (const float*)d_in[1];
  const float* qkv_b  = (const float*)d_in[2];
  const float* btab   = (const float*)d_in[3];
  const float* proj_w = (const float*)d_in[4];
  const float* proj_b = (const float*)d_in[5];
  float* out = (float*)d_out;

  char* ws = (char*)d_ws;
  const size_t ATT = 51380224ULL;   // 50176*512*2
  const size_t XB  = 51380224ULL;
  const size_t WQ  = 1572864ULL;
  const size_t WP  = 524288ULL;
  const size_t BT  = 262144ULL;     // 16*64*64*4
  const size_t need_big = ATT + XB + WQ + WP + BT + 8192;

  if (ws_size >= need_big){
    unsigned short* att     = (unsigned short*)ws;
    unsigned short* xbb     = (unsigned short*)(ws + ATT);
    unsigned short* wqkv_t  = (unsigned short*)(ws + ATT + XB);
    unsigned short* wproj_t = (unsigned short*)(ws + ATT + XB + WQ);
    float*          bias_t  = (float*)(ws + ATT + XB + WQ + WP);
    float*          bqkv_s  = (float*)(ws + ATT + XB + WQ + WP + BT);

    k_prep2<<<12544 + 512, 256, 0, stream>>>(x, qkv_w, qkv_b, proj_w, btab,
                                             xbb, wqkv_t, wproj_t, bqkv_s, bias_t);
    k_qkv_attn8<<<1024*4, 256, 0, stream>>>(xbb, wqkv_t, bqkv_s, bias_t, att);
    k_proj<<<392*4, 256, 0, stream>>>(att, wproj_t, proj_b, out);
  } else {
    unsigned short* att     = (unsigned short*)ws;
    unsigned short* wqkv_t  = (unsigned short*)(ws + ATT);
    unsigned short* wproj_t = (unsigned short*)(ws + ATT + WQ);
    float*          bqkv_s  = (float*)(ws + ATT + WQ + WP);

    k_prep2<<<12544 + 512, 256, 0, stream>>>(x, qkv_w, qkv_b, proj_w, btab,
                                             att /*scratch, overwritten later*/,
                                             wqkv_t, wproj_t, bqkv_s,
                                             (float*)(ws + ATT + WQ + WP + 8192));
    k_qkv_attn_f32<<<1024*4, 256, 0, stream>>>(x, wqkv_t, bqkv_s, btab, att);
    k_proj<<<392*4, 256, 0, stream>>>(att, wproj_t, proj_b, out);
  }
}

// Round 10
// 292.772 us; speedup vs baseline: 1.4695x; 1.1878x over previous
//
#include <hip/hip_runtime.h>
#include <hip/hip_bf16.h>

typedef __attribute__((ext_vector_type(4))) float f32x4;
typedef __attribute__((ext_vector_type(8))) short s16x8;

#define MFMA16(a,b,c) __builtin_amdgcn_mfma_f32_16x16x32_bf16(a,b,c,0,0,0)

__device__ __forceinline__ unsigned short f2bf(float f){
  __hip_bfloat16 h = __float2bfloat16(f);
  return *reinterpret_cast<unsigned short*>(&h);
}

__device__ __forceinline__ void gload_lds16(const unsigned short* g, unsigned short* l){
  __builtin_amdgcn_global_load_lds(
      (const __attribute__((address_space(1))) unsigned int*)(const void*)g,
      (__attribute__((address_space(3))) unsigned int*)(void*)l,
      16, 0, 0);
}

// ---------------- fused x->bf16 cast + weight prep -------------------------
__global__ void k_prep2(const float* __restrict__ x,
                        const float* __restrict__ qkv_w,   // (512,1536)
                        const float* __restrict__ qkv_b,   // (1536)
                        const float* __restrict__ proj_w,  // (512,512)
                        const float* __restrict__ btab,    // (169,16)
                        unsigned short* __restrict__ xb,      // (50176,512) bf16
                        unsigned short* __restrict__ wqkv_t,  // (1536,512) bf16
                        unsigned short* __restrict__ wproj_t, // (512,512) bf16
                        float* __restrict__ bqkv_s,           // (1536) f32
                        float* __restrict__ bias_t)           // (16,64,64) f32
{
  if (blockIdx.x < 12544){
    const int i = blockIdx.x * 256 + threadIdx.x;   // one 8-elem chunk
    const float* p = x + (size_t)i*8;
    f32x4 v0 = *(const f32x4*)p, v1 = *(const f32x4*)(p+4);
    s16x8 t;
    t[0]=(short)f2bf(v0[0]); t[1]=(short)f2bf(v0[1]);
    t[2]=(short)f2bf(v0[2]); t[3]=(short)f2bf(v0[3]);
    t[4]=(short)f2bf(v1[0]); t[5]=(short)f2bf(v1[1]);
    t[6]=(short)f2bf(v1[2]); t[7]=(short)f2bf(v1[3]);
    *(s16x8*)(xb + (size_t)i*8) = t;
    return;
  }
  const float scale = 0.17677669529663687f; // 32^-0.5
  int tid = (blockIdx.x - 12544) * 256 + threadIdx.x;
  int np  = 512 * 256;
  for (int i = tid; i < 1536*512; i += np){
    int c = i >> 9, k = i & 511;
    float w = qkv_w[k*1536 + c];
    if (c < 512) w *= scale;
    wqkv_t[i] = f2bf(w);
  }
  for (int i = tid; i < 512*512; i += np){
    int c = i >> 9, k = i & 511;
    wproj_t[i] = f2bf(proj_w[k*512 + c]);
  }
  for (int i = tid; i < 1536; i += np){
    float bv = qkv_b[i];
    if (i < 512) bv *= scale;
    bqkv_s[i] = bv;
  }
  for (int i = tid; i < 16*64*64; i += np){
    int hh = i >> 12, rc = i & 4095, row = rc >> 6, col = rc & 63;
    float v;
    if (col >= 49)      v = -1e30f;
    else if (row >= 49) v = 0.f;
    else {
      int qy = row/7, qx = row%7, ky = col/7, kx = col%7;
      v = btab[((qy-ky+6)*13 + (qx-kx+6))*16 + hh];
    }
    bias_t[i] = v;
  }
}

// ---------------- fused qkv GEMM + window attention (unchanged, R9) --------
__global__ __launch_bounds__(256, 3) void k_qkv_attn8(
    const unsigned short* __restrict__ xb,    // (50176,512) bf16
    const unsigned short* __restrict__ wqkv_t,// (1536,512) bf16 (q pre-scaled)
    const float* __restrict__ bqkv_s,         // (1536) f32 (q pre-scaled)
    const float* __restrict__ bias_t,         // (16,64,64) f32, mask folded
    unsigned short* __restrict__ att)         // (1024,49,512) bf16
{
  __shared__ unsigned short lds[4*5120 + 2*2048];
  const int lane = threadIdx.x & 63;
  const int wave = threadIdx.x >> 6;
  const int bid  = blockIdx.x;
  const int xcd  = bid & 7;
  const int g    = (bid >> 3) & 3;
  const int wblk = bid >> 5;
  const int b    = xcd + (wblk << 3);
  const int h    = (g << 2) | wave;
  const int l16  = lane & 15;
  const int lg   = lane >> 4;   // 0..3
  const f32x4 ZERO4 = {0.f, 0.f, 0.f, 0.f};

  unsigned short* q_lds  = lds + wave*5120;   // [64][40]
  unsigned short* k_lds  = q_lds + 2560;      // [64][40]
  unsigned short* p_lds  = q_lds;             // [64][72] overlay (q+k dead)
  unsigned short* xstage = lds + 4*5120;      // [2][64][32]

  for (int i = threadIdx.x; i < 2*15*32; i += 256){
    int bf = i / 480, rem = i % 480;
    xstage[bf*2048 + (49 + rem/32)*32 + (rem & 31)] = 0;
  }

  const unsigned short* xwin = xb + (size_t)b*49*512;
  const int srow = wave*16 + (lane>>2);
  const int cbase = h * 32;
  const unsigned short* xsrc = xwin + (size_t)srow*512 + (lane&3)*8;

  const unsigned short* bbase =
      wqkv_t + (size_t)(cbase + l16)*512 + lg*8;

  __syncthreads();
  if (srow < 49) gload_lds16(xsrc, xstage + wave*512);
  __syncthreads();

  f32x4 acc[3][4][2];
  #pragma unroll
  for (int a=0;a<3;++a)
    #pragma unroll
    for (int rt=0;rt<4;++rt)
      #pragma unroll
      for (int ct=0;ct<2;++ct)
        acc[a][rt][ct] = ZERO4;

  #pragma unroll 2
  for (int ks = 0; ks < 16; ++ks){
    const int p = ks & 1;

    s16x8 bfrag[6];
    #pragma unroll
    for (int wq=0; wq<3; ++wq)
      #pragma unroll
      for (int ct=0; ct<2; ++ct)
        bfrag[wq*2+ct] = *(const s16x8*)(bbase + wq*262144 + ct*8192 + ks*32);

    if (ks < 15 && srow < 49)
      gload_lds16(xsrc + (ks+1)*32, xstage + ((ks+1)&1)*2048 + wave*512);

    s16x8 afrag[4];
    #pragma unroll
    for (int rt=0; rt<4; ++rt)
      afrag[rt] = *(const s16x8*)&xstage[p*2048 + (rt*16 + l16)*32 + lg*8];

    #pragma unroll
    for (int wq=0;wq<3;++wq)
      #pragma unroll
      for (int rt=0;rt<4;++rt)
        #pragma unroll
        for (int ct=0;ct<2;++ct)
          acc[wq][rt][ct] = MFMA16(afrag[rt], bfrag[wq*2+ct], acc[wq][rt][ct]);

    __syncthreads();
  }

  uint2 vpk[4][2];
  #pragma unroll
  for (int wq=0; wq<3; ++wq){
    #pragma unroll
    for (int ct=0; ct<2; ++ct){
      const int c = wq*512 + cbase + ct*16 + l16;
      const float bv = bqkv_s[c];
      #pragma unroll
      for (int rt=0; rt<4; ++rt){
        f32x4 vv = acc[wq][rt][ct];
        const int row0 = rt*16 + lg*4;
        if (wq == 0){
          #pragma unroll
          for (int r=0;r<4;++r) q_lds[(row0+r)*40 + ct*16 + l16] = f2bf(vv[r]+bv);
        } else if (wq == 1){
          #pragma unroll
          for (int r=0;r<4;++r) k_lds[(row0+r)*40 + ct*16 + l16] = f2bf(vv[r]+bv);
        } else {
          uint2 pk;
          pk.x = (unsigned)f2bf(vv[0]+bv) | ((unsigned)f2bf(vv[1]+bv) << 16);
          pk.y = (unsigned)f2bf(vv[2]+bv) | ((unsigned)f2bf(vv[3]+bv) << 16);
          vpk[rt][ct] = pk;
        }
      }
    }
  }

  s16x8 aq[4], bk[4];
  #pragma unroll
  for (int t=0;t<4;++t){
    aq[t] = *(const s16x8*)&q_lds[(t*16+l16)*40 + lg*8];
    bk[t] = *(const s16x8*)&k_lds[(t*16+l16)*40 + lg*8];
  }
  f32x4 sacc[4][4];
  #pragma unroll
  for (int rt=0;rt<4;++rt)
    #pragma unroll
    for (int ct=0;ct<4;++ct)
      sacc[rt][ct] = MFMA16(aq[rt], bk[ct], ZERO4);

  const float* biash = bias_t + (h << 12);
  float pm[4][4];
  #pragma unroll
  for (int rt=0;rt<4;++rt){
    #pragma unroll
    for (int r=0;r<4;++r){
      const int row = rt*16 + lg*4 + r;
      const float* brow = biash + (row << 6) + l16;
      float s0 = sacc[rt][0][r] + brow[0];
      float s1 = sacc[rt][1][r] + brow[16];
      float s2 = sacc[rt][2][r] + brow[32];
      float s3 = sacc[rt][3][r] + brow[48];
      sacc[rt][0][r]=s0; sacc[rt][1][r]=s1; sacc[rt][2][r]=s2; sacc[rt][3][r]=s3;
      pm[rt][r] = fmaxf(fmaxf(s0,s1), fmaxf(s2,s3));
    }
  }
  #pragma unroll
  for (int d=1; d<16; d<<=1)
    #pragma unroll
    for (int rt=0;rt<4;++rt)
      #pragma unroll
      for (int r=0;r<4;++r)
        pm[rt][r] = fmaxf(pm[rt][r], __shfl_xor(pm[rt][r], d));

  float ps[4][4];
  #pragma unroll
  for (int rt=0;rt<4;++rt){
    #pragma unroll
    for (int r=0;r<4;++r){
      const float m = pm[rt][r];
      float e0 = __expf(sacc[rt][0][r]-m), e1 = __expf(sacc[rt][1][r]-m);
      float e2 = __expf(sacc[rt][2][r]-m), e3 = __expf(sacc[rt][3][r]-m);
      sacc[rt][0][r]=e0; sacc[rt][1][r]=e1; sacc[rt][2][r]=e2; sacc[rt][3][r]=e3;
      ps[rt][r] = e0+e1+e2+e3;
    }
  }
  #pragma unroll
  for (int d=1; d<16; d<<=1)
    #pragma unroll
    for (int rt=0;rt<4;++rt)
      #pragma unroll
      for (int r=0;r<4;++r)
        ps[rt][r] += __shfl_xor(ps[rt][r], d);

  #pragma unroll
  for (int rt=0;rt<4;++rt){
    #pragma unroll
    for (int r=0;r<4;++r){
      const int row = rt*16 + lg*4 + r;
      const float inv = 1.f / ps[rt][r];
      p_lds[row*72 +      l16] = f2bf(sacc[rt][0][r]*inv);
      p_lds[row*72 + 16 + l16] = f2bf(sacc[rt][1][r]*inv);
      p_lds[row*72 + 32 + l16] = f2bf(sacc[rt][2][r]*inv);
      p_lds[row*72 + 48 + l16] = f2bf(sacc[rt][3][r]*inv);
    }
  }

  const int srcA = l16 + ((lg & 1) << 5);
  const int srcB = srcA + 16;
  const bool hiSel = (lg >> 1) != 0;

  f32x4 oacc[4][2];
  #pragma unroll
  for (int rt=0;rt<4;++rt)
    #pragma unroll
    for (int ct=0;ct<2;++ct)
      oacc[rt][ct] = ZERO4;

  #pragma unroll
  for (int kt=0; kt<2; ++kt){
    s16x8 ap[4], bv2[2];
    #pragma unroll
    for (int rt=0;rt<4;++rt)
      ap[rt] = *(const s16x8*)&p_lds[(rt*16+l16)*72 + kt*32 + lg*8];
    #pragma unroll
    for (int ct=0;ct<2;++ct){
      unsigned a0x = (unsigned)__shfl((int)vpk[2*kt  ][ct].x, srcA, 64);
      unsigned a0y = (unsigned)__shfl((int)vpk[2*kt  ][ct].y, srcA, 64);
      unsigned a1x = (unsigned)__shfl((int)vpk[2*kt+1][ct].x, srcA, 64);
      unsigned a1y = (unsigned)__shfl((int)vpk[2*kt+1][ct].y, srcA, 64);
      unsigned b0x = (unsigned)__shfl((int)vpk[2*kt  ][ct].x, srcB, 64);
      unsigned b0y = (unsigned)__shfl((int)vpk[2*kt  ][ct].y, srcB, 64);
      unsigned b1x = (unsigned)__shfl((int)vpk[2*kt+1][ct].x, srcB, 64);
      unsigned b1y = (unsigned)__shfl((int)vpk[2*kt+1][ct].y, srcB, 64);
      union { s16x8 v; unsigned u[4]; } fr;
      fr.u[0] = hiSel ? a1x : a0x;
      fr.u[1] = hiSel ? a1y : a0y;
      fr.u[2] = hiSel ? b1x : b0x;
      fr.u[3] = hiSel ? b1y : b0y;
      bv2[ct] = fr.v;
    }
    #pragma unroll
    for (int rt=0;rt<4;++rt)
      #pragma unroll
      for (int ct=0;ct<2;++ct)
        oacc[rt][ct] = MFMA16(ap[rt], bv2[ct], oacc[rt][ct]);
  }

  unsigned short* o_lds = p_lds;  // [64][40]
  #pragma unroll
  for (int rt=0;rt<4;++rt)
    #pragma unroll
    for (int ct=0;ct<2;++ct){
      const int row0 = rt*16 + lg*4;
      f32x4 vv = oacc[rt][ct];
      #pragma unroll
      for (int r=0;r<4;++r)
        o_lds[(row0+r)*40 + ct*16 + l16] = f2bf(vv[r]);
    }
  unsigned short* attb = att + (size_t)b*49*512 + h*32;
  for (int i = lane; i < 49*4; i += 64){
    const int row = i >> 2, seg = i & 3;
    *(s16x8*)&attb[(size_t)row*512 + seg*8] = *(const s16x8*)&o_lds[row*40 + seg*8];
  }
}

// ---------------- fallback (f32 x direct, small ws) ------------------------
__global__ __launch_bounds__(256, 2) void k_qkv_attn_f32(
    const float* __restrict__ x,
    const unsigned short* __restrict__ wqkv_t,
    const float* __restrict__ bqkv_s,
    const float* __restrict__ btab,
    unsigned short* __restrict__ att)
{
  __shared__ unsigned short lds[4*7424];
  const int lane = threadIdx.x & 63;
  const int wave = threadIdx.x >> 6;
  const int b    = blockIdx.x >> 2;
  const int h    = ((blockIdx.x & 3) << 2) | wave;
  const int l16  = lane & 15;
  const int lg   = lane >> 4;
  const f32x4 ZERO4 = {0.f, 0.f, 0.f, 0.f};

  unsigned short* q_lds = lds + wave*7424;
  unsigned short* k_lds = q_lds + 2560;
  unsigned short* vT    = q_lds + 5120;
  unsigned short* p_lds = q_lds;

  f32x4 acc[3][4][2];
  #pragma unroll
  for (int a=0;a<3;++a)
    #pragma unroll
    for (int rt=0;rt<4;++rt)
      #pragma unroll
      for (int ct=0;ct<2;++ct)
        acc[a][rt][ct] = ZERO4;

  const float* xbp = x + (size_t)b * 49 * 512;
  const int cbase = h * 32;

  #pragma unroll 2
  for (int ks = 0; ks < 16; ++ks){
    const int k0 = ks*32 + lg*8;
    s16x8 afrag[4];
    #pragma unroll
    for (int rt=0; rt<4; ++rt){
      const int n = rt*16 + l16;
      f32x4 v0 = ZERO4, v1 = ZERO4;
      if (n < 49){
        const float* p = xbp + n*512 + k0;
        v0 = *(const f32x4*)p;
        v1 = *(const f32x4*)(p + 4);
      }
      s16x8 t;
      t[0]=(short)f2bf(v0[0]); t[1]=(short)f2bf(v0[1]);
      t[2]=(short)f2bf(v0[2]); t[3]=(short)f2bf(v0[3]);
      t[4]=(short)f2bf(v1[0]); t[5]=(short)f2bf(v1[1]);
      t[6]=(short)f2bf(v1[2]); t[7]=(short)f2bf(v1[3]);
      afrag[rt] = t;
    }
    s16x8 bfrag[3][2];
    #pragma unroll
    for (int wq=0;wq<3;++wq)
      #pragma unroll
      for (int ct=0;ct<2;++ct){
        const int c = wq*512 + cbase + ct*16 + l16;
        bfrag[wq][ct] = *(const s16x8*)(wqkv_t + (size_t)c*512 + k0);
      }
    #pragma unroll
    for (int wq=0;wq<3;++wq)
      #pragma unroll
      for (int rt=0;rt<4;++rt)
        #pragma unroll
        for (int ct=0;ct<2;++ct)
          acc[wq][rt][ct] = MFMA16(afrag[rt], bfrag[wq][ct], acc[wq][rt][ct]);
  }

  #pragma unroll
  for (int wq=0; wq<3; ++wq){
    #pragma unroll
    for (int ct=0; ct<2; ++ct){
      const int c = wq*512 + cbase + ct*16 + l16;
      const float bv = bqkv_s[c];
      #pragma unroll
      for (int rt=0; rt<4; ++rt){
        f32x4 vv = acc[wq][rt][ct];
        const int row0 = rt*16 + lg*4;
        if (wq == 0){
          #pragma unroll
          for (int r=0;r<4;++r) q_lds[(row0+r)*40 + ct*16 + l16] = f2bf(vv[r]+bv);
        } else if (wq == 1){
          #pragma unroll
          for (int r=0;r<4;++r) k_lds[(row0+r)*40 + ct*16 + l16] = f2bf(vv[r]+bv);
        } else {
          ushort4 pk;
          pk.x=f2bf(vv[0]+bv); pk.y=f2bf(vv[1]+bv);
          pk.z=f2bf(vv[2]+bv); pk.w=f2bf(vv[3]+bv);
          *(ushort4*)&vT[(ct*16+l16)*72 + row0] = pk;
        }
      }
    }
  }

  s16x8 aq[4], bk[4];
  #pragma unroll
  for (int t=0;t<4;++t){
    aq[t] = *(const s16x8*)&q_lds[(t*16+l16)*40 + lg*8];
    bk[t] = *(const s16x8*)&k_lds[(t*16+l16)*40 + lg*8];
  }
  f32x4 sacc[4][4];
  #pragma unroll
  for (int rt=0;rt<4;++rt)
    #pragma unroll
    for (int ct=0;ct<4;++ct)
      sacc[rt][ct] = MFMA16(aq[rt], bk[ct], ZERO4);

  int colv[4], kyv[4], kxv[4];
  #pragma unroll
  for (int ct=0;ct<4;++ct){
    colv[ct] = ct*16 + l16;
    kyv[ct]  = colv[ct] / 7;
    kxv[ct]  = colv[ct] % 7;
  }
  #pragma unroll
  for (int rt=0;rt<4;++rt){
    #pragma unroll
    for (int r=0;r<4;++r){
      const int row = rt*16 + lg*4 + r;
      const int qy = row / 7, qx = row % 7;
      float sv[4];
      #pragma unroll
      for (int ct=0;ct<4;++ct){
        float s = sacc[rt][ct][r];
        if (row < 49 && colv[ct] < 49){
          const int idx = (qy - kyv[ct] + 6)*13 + (qx - kxv[ct] + 6);
          s += btab[idx*16 + h];
        }
        if (colv[ct] >= 49) s = -1e30f;
        else if (row >= 49) s = 0.f;
        sv[ct] = s;
      }
      float m = fmaxf(fmaxf(sv[0],sv[1]), fmaxf(sv[2],sv[3]));
      #pragma unroll
      for (int d=1; d<16; d<<=1) m = fmaxf(m, __shfl_xor(m, d));
      float e0 = __expf(sv[0]-m), e1 = __expf(sv[1]-m);
      float e2 = __expf(sv[2]-m), e3 = __expf(sv[3]-m);
      float sum = e0+e1+e2+e3;
      #pragma unroll
      for (int d=1; d<16; d<<=1) sum += __shfl_xor(sum, d);
      const float inv = 1.f / sum;
      p_lds[row*72 + colv[0]] = f2bf(e0*inv);
      p_lds[row*72 + colv[1]] = f2bf(e1*inv);
      p_lds[row*72 + colv[2]] = f2bf(e2*inv);
      p_lds[row*72 + colv[3]] = f2bf(e3*inv);
    }
  }

  f32x4 oacc[4][2];
  #pragma unroll
  for (int rt=0;rt<4;++rt)
    #pragma unroll
    for (int ct=0;ct<2;++ct)
      oacc[rt][ct] = ZERO4;
  #pragma unroll
  for (int kt=0; kt<2; ++kt){
    s16x8 ap[4], bv2[2];
    #pragma unroll
    for (int rt=0;rt<4;++rt)
      ap[rt] = *(const s16x8*)&p_lds[(rt*16+l16)*72 + kt*32 + lg*8];
    #pragma unroll
    for (int ct=0;ct<2;++ct)
      bv2[ct] = *(const s16x8*)&vT[(ct*16+l16)*72 + kt*32 + lg*8];
    #pragma unroll
    for (int rt=0;rt<4;++rt)
      #pragma unroll
      for (int ct=0;ct<2;++ct)
        oacc[rt][ct] = MFMA16(ap[rt], bv2[ct], oacc[rt][ct]);
  }

  unsigned short* o_lds = p_lds;
  #pragma unroll
  for (int rt=0;rt<4;++rt)
    #pragma unroll
    for (int ct=0;ct<2;++ct){
      const int row0 = rt*16 + lg*4;
      f32x4 vv = oacc[rt][ct];
      #pragma unroll
      for (int r=0;r<4;++r)
        o_lds[(row0+r)*40 + ct*16 + l16] = f2bf(vv[r]);
    }
  unsigned short* attb = att + (size_t)b*49*512 + h*32;
  for (int i = lane; i < 49*4; i += 64){
    const int row = i >> 2, seg = i & 3;
    *(s16x8*)&attb[(size_t)row*512 + seg*8] = *(const s16x8*)&o_lds[row*40 + seg*8];
  }
}

// ---------------- proj GEMM, m97-style: 128x128 tile, gload_lds dbuf -------
// grid 1568 = 8 XCDs x (4 nb x 49 mgrp); mb contiguous per XCD (A-panel L2).
// LDS: A dbuf [2][128][32] + B dbuf [2][128][32] bf16 = 32 KB.
// Per K-step: 4 gload_lds16/thread prefetch, 8 ds_read_b128/wave, 16 MFMA.
__global__ __launch_bounds__(256) void k_proj2(
    const unsigned short* __restrict__ att,    // (50176,512) bf16
    const unsigned short* __restrict__ wproj_t,// (512,512) bf16, [n][k]
    const float* __restrict__ proj_b,          // (512)
    float* __restrict__ out)                   // (50176,512) f32
{
  __shared__ unsigned short lds[16384];   // A:[0,8192) dbuf, B:[8192,16384) dbuf
  const int t    = threadIdx.x;
  const int lane = t & 63;
  const int wave = t >> 6;
  const int l16  = lane & 15;
  const int lg   = lane >> 4;
  const int wr   = wave >> 1;   // 0..1 row-half
  const int wc   = wave & 1;    // 0..1 col-half
  const f32x4 ZERO4 = {0.f, 0.f, 0.f, 0.f};

  // XCD-bijective decode: 1568 = 8 * (4 nb * 49 mgrp); 392 = 8*49
  const int bid  = blockIdx.x;
  const int xcd  = bid & 7;
  const int idx  = bid >> 3;
  const int nb   = idx & 3;
  const int mgrp = idx >> 2;          // 0..48
  const int mb   = xcd*49 + mgrp;     // 0..391
  const int m0   = mb * 128;
  const int n0   = nb * 128;

  // staging: thread t stages row (half*64 + t/4), 16B at col (t%4)*8 shorts
  const int srow = t >> 2;
  const int scol = (t & 3) * 8;
  const unsigned short* asrc = att     + (size_t)(m0 + srow)*512 + scol;
  const unsigned short* bsrc = wproj_t + (size_t)(n0 + srow)*512 + scol;

  // prologue: stage K-tile 0 into buffer 0
  gload_lds16(asrc,          lds + wave*512);
  gload_lds16(asrc + 32768,  lds + 2048 + wave*512);          // +64 rows
  gload_lds16(bsrc,          lds + 8192 + wave*512);
  gload_lds16(bsrc + 32768,  lds + 8192 + 2048 + wave*512);
  __syncthreads();

  f32x4 acc[4][4];
  #pragma unroll
  for (int rt=0;rt<4;++rt)
    #pragma unroll
    for (int ct=0;ct<4;++ct)
      acc[rt][ct] = ZERO4;

  #pragma unroll 2
  for (int ks = 0; ks < 16; ++ks){
    const int p = ks & 1;
    unsigned short* Ab = lds + p*4096;
    unsigned short* Bb = lds + 8192 + p*4096;

    // prefetch next K-tile into the other buffer
    if (ks < 15){
      const int q = (ks+1) & 1;
      const unsigned short* a2 = asrc + (ks+1)*32;
      const unsigned short* b2 = bsrc + (ks+1)*32;
      gload_lds16(a2,         lds + q*4096 + wave*512);
      gload_lds16(a2 + 32768, lds + q*4096 + 2048 + wave*512);
      gload_lds16(b2,         lds + 8192 + q*4096 + wave*512);
      gload_lds16(b2 + 32768, lds + 8192 + q*4096 + 2048 + wave*512);
    }

    s16x8 af[4], bf[4];
    #pragma unroll
    for (int rt=0;rt<4;++rt)
      af[rt] = *(const s16x8*)&Ab[(wr*64 + rt*16 + l16)*32 + lg*8];
    #pragma unroll
    for (int ct=0;ct<4;++ct)
      bf[ct] = *(const s16x8*)&Bb[(wc*64 + ct*16 + l16)*32 + lg*8];

    #pragma unroll
    for (int rt=0;rt<4;++rt)
      #pragma unroll
      for (int ct=0;ct<4;++ct)
        acc[rt][ct] = MFMA16(af[rt], bf[ct], acc[rt][ct]);

    __syncthreads();
  }

  #pragma unroll
  for (int ct=0;ct<4;++ct){
    const int col = n0 + wc*64 + ct*16 + l16;
    const float bv = proj_b[col];
    #pragma unroll
    for (int rt=0;rt<4;++rt){
      const int row = m0 + wr*64 + rt*16 + lg*4;
      #pragma unroll
      for (int r=0;r<4;++r)
        out[(size_t)(row+r)*512 + col] = acc[rt][ct][r] + bv;
    }
  }
}

// ---------------- launcher -------------------------------------------------
extern "C" void kernel_launch(void* const* d_in, const int* in_sizes, int n_in,
                              void* d_out, int out_size, void* d_ws, size_t ws_size,
                              hipStream_t stream)
{
  const float* x      = (const float*)d_in[0];
  const float* qkv_w  = (const float*)d_in[1];
  const float* qkv_b  = (const float*)d_in[2];
  const float* btab   = (const float*)d_in[3];
  const float* proj_w = (const float*)d_in[4];
  const float* proj_b = (const float*)d_in[5];
  float* out = (float*)d_out;

  char* ws = (char*)d_ws;
  const size_t ATT = 51380224ULL;   // 50176*512*2
  const size_t XB  = 51380224ULL;
  const size_t WQ  = 1572864ULL;
  const size_t WP  = 524288ULL;
  const size_t BT  = 262144ULL;     // 16*64*64*4
  const size_t need_big = ATT + XB + WQ + WP + BT + 8192;

  if (ws_size >= need_big){
    unsigned short* att     = (unsigned short*)ws;
    unsigned short* xbb     = (unsigned short*)(ws + ATT);
    unsigned short* wqkv_t  = (unsigned short*)(ws + ATT + XB);
    unsigned short* wproj_t = (unsigned short*)(ws + ATT + XB + WQ);
    float*          bias_t  = (float*)(ws + ATT + XB + WQ + WP);
    float*          bqkv_s  = (float*)(ws + ATT + XB + WQ + WP + BT);

    k_prep2<<<12544 + 512, 256, 0, stream>>>(x, qkv_w, qkv_b, proj_w, btab,
                                             xbb, wqkv_t, wproj_t, bqkv_s, bias_t);
    k_qkv_attn8<<<1024*4, 256, 0, stream>>>(xbb, wqkv_t, bqkv_s, bias_t, att);
    k_proj2<<<392*4, 256, 0, stream>>>(att, wproj_t, proj_b, out);
  } else {
    unsigned short* att     = (unsigned short*)ws;
    unsigned short* wqkv_t  = (unsigned short*)(ws + ATT);
    unsigned short* wproj_t = (unsigned short*)(ws + ATT + WQ);
    float*          bqkv_s  = (float*)(ws + ATT + WQ + WP);

    k_prep2<<<12544 + 512, 256, 0, stream>>>(x, qkv_w, qkv_b, proj_w, btab,
                                             att /*scratch, overwritten later*/,
                                             wqkv_t, wproj_t, bqkv_s,
                                             (float*)(ws + ATT + WQ + WP + 8192));
    k_qkv_attn_f32<<<1024*4, 256, 0, stream>>>(x, wqkv_t, bqkv_s, btab, att);
    k_proj2<<<392*4, 256, 0, stream>>>(att, wproj_t, proj_b, out);
  }
}